// Round 4
// baseline (323.742 us; speedup 1.0000x reference)
//
#include <hip/hip_runtime.h>
#include <hip/hip_bf16.h>

// Transformer block: x[2,2048,768] fp32. All GEMMs in bf16 MFMA (16x16x32),
// fp32 accumulate. N=768 GEMMs (Wo, FF2) use split-K with bf16 partials.
// Attention: S^T = K.Q^T via 16x16x16 MFMA so P^T's C-frag IS the B-frag of
// O^T = V^T.P^T (no LDS round-trip); fixed-shift softmax, split over keys.

typedef unsigned short u16;
typedef unsigned int u32;
typedef __attribute__((ext_vector_type(8))) short s16x8;   // 8 bf16 (4 VGPR)
typedef __attribute__((ext_vector_type(4))) short s16x4;   // 4 bf16 (2 VGPR)
typedef __attribute__((ext_vector_type(4))) float fx4;     // 4 fp32 acc

#define D_MODEL 768
#define NH 12
#define HS 64
#define TT 2048
#define BB 2

__device__ __forceinline__ u16 f2bf(float f) {
  union { float f; u32 u; } v; v.f = f;
  u32 r = v.u + 0x7fffu + ((v.u >> 16) & 1u);   // RNE
  return (u16)(r >> 16);
}
__device__ __forceinline__ float bf2f(u16 h) {
  union { u32 u; float f; } v; v.u = ((u32)h) << 16; return v.f;
}
__device__ __forceinline__ s16x4 pack4(float a, float b, float c, float d) {
  union { __hip_bfloat162 h2[2]; s16x4 v; } u;
  u.h2[0] = __float22bfloat162_rn({a, b});
  u.h2[1] = __float22bfloat162_rn({c, d});
  return u.v;
}

// async global->LDS, 16B per lane; LDS dest = wave-uniform base + lane*16
__device__ __forceinline__ void async16(const void* g, void* l) {
  __builtin_amdgcn_global_load_lds(
      (const __attribute__((address_space(1))) u32*)g,
      (__attribute__((address_space(3))) u32*)l, 16, 0, 0);
}

// swizzled b64 read from a [rows][64 bf16] LDS tile staged with chunk^(row&7)
__device__ __forceinline__ s16x4 lds_rd64(const u16* base, int row, int g) {
  int a = row * 64 + ((((g >> 1) ^ (row & 7)) << 3) | ((g & 1) << 2));
  return *(const s16x4*)(base + a);
}

// ---------------- transpose + fp32->bf16 convert: in[R][C] -> out[C][R] ----
__global__ __launch_bounds__(256) void tconv(const float* __restrict__ in,
                                             u16* __restrict__ out, int R, int C) {
  __shared__ float t[32][33];
  int c0 = blockIdx.x * 32, r0 = blockIdx.y * 32;
  int x = threadIdx.x, y = threadIdx.y;
  for (int i = 0; i < 4; i++)
    t[y + i * 8][x] = in[(size_t)(r0 + y + i * 8) * C + c0 + x];
  __syncthreads();
  for (int i = 0; i < 4; i++)
    out[(size_t)(c0 + y + i * 8) * R + r0 + x] = f2bf(t[x][y + i * 8]);
}

// three 768x768 transposes in one launch (z selects Wq/Wk/Wv)
__global__ __launch_bounds__(256) void tconv3(const float* __restrict__ w0,
                                              const float* __restrict__ w1,
                                              const float* __restrict__ w2,
                                              u16* __restrict__ out) {
  __shared__ float t[32][33];
  const float* in = blockIdx.z == 0 ? w0 : blockIdx.z == 1 ? w1 : w2;
  u16* o = out + (size_t)blockIdx.z * 768 * 768;
  int c0 = blockIdx.x * 32, r0 = blockIdx.y * 32;
  int x = threadIdx.x, y = threadIdx.y;
  for (int i = 0; i < 4; i++)
    t[y + i * 8][x] = in[(size_t)(r0 + y + i * 8) * 768 + c0 + x];
  __syncthreads();
  for (int i = 0; i < 4; i++)
    o[(size_t)(c0 + y + i * 8) * 768 + r0 + x] = f2bf(t[x][y + i * 8]);
}

// ---------------- V^T extraction: QKV[4096][2304] -> Vt[24][64][2048] ------
__global__ __launch_bounds__(256) void vt_extract(const u16* __restrict__ qkv,
                                                  u16* __restrict__ vt) {
  __shared__ u16 t[32][33];
  int bh = blockIdx.z, b = bh / NH, h = bh % NH;
  int t0 = blockIdx.x * 32, v0 = blockIdx.y * 32;
  int x = threadIdx.x, y = threadIdx.y;
  for (int i = 0; i < 4; i++)
    t[y + i * 8][x] = qkv[(size_t)(b * TT + t0 + y + i * 8) * 2304 + 1536 + h * HS + v0 + x];
  __syncthreads();
  for (int i = 0; i < 4; i++)
    vt[(size_t)(bh * HS + v0 + y + i * 8) * TT + t0 + x] = t[x][y + i * 8];
}

// ---------------- mask -> additive bias (log2 domain) ----------------------
__global__ __launch_bounds__(256) void maskbias(const int* __restrict__ mask,
                                                float* __restrict__ mb) {
  int i = blockIdx.x * 256 + threadIdx.x;
  mb[i] = mask[i] ? 0.f : -1e30f;
}

// ---------------- LayerNorm: fp32 row[768] -> bf16 ------------------------
__global__ __launch_bounds__(256) void ln_kernel(const float* __restrict__ x,
                                                 const float* __restrict__ g,
                                                 const float* __restrict__ bta,
                                                 u16* __restrict__ out) {
  int row = blockIdx.x;
  const float* xr = x + (size_t)row * D_MODEL;
  int tid = threadIdx.x;
  float v0 = xr[tid], v1 = xr[tid + 256], v2 = xr[tid + 512];
  float s = v0 + v1 + v2, sq = v0 * v0 + v1 * v1 + v2 * v2;
  for (int m = 1; m < 64; m <<= 1) { s += __shfl_xor(s, m); sq += __shfl_xor(sq, m); }
  __shared__ float ss[4], ssq[4];
  int w = tid >> 6;
  if ((tid & 63) == 0) { ss[w] = s; ssq[w] = sq; }
  __syncthreads();
  s = ss[0] + ss[1] + ss[2] + ss[3];
  sq = ssq[0] + ssq[1] + ssq[2] + ssq[3];
  float mean = s * (1.f / D_MODEL);
  float var = sq * (1.f / D_MODEL) - mean * mean;
  float rstd = rsqrtf(var + 1e-5f);
  u16* orow = out + (size_t)row * D_MODEL;
  orow[tid]       = f2bf((v0 - mean) * rstd * g[tid]       + bta[tid]);
  orow[tid + 256] = f2bf((v1 - mean) * rstd * g[tid + 256] + bta[tid + 256]);
  orow[tid + 512] = f2bf((v2 - mean) * rstd * g[tid + 512] + bta[tid + 512]);
}

// ---- partial-sum(4, bf16) + residual + bias + LayerNorm -> yv fp32, h2 bf16
__global__ __launch_bounds__(256) void red_wo_ln(
    const u16* __restrict__ p0, const u16* __restrict__ p1,
    const u16* __restrict__ p2, const u16* __restrict__ p3,
    const float* __restrict__ x, const float* __restrict__ bo,
    const float* __restrict__ g, const float* __restrict__ be,
    float* __restrict__ yv, u16* __restrict__ h2) {
  int row = blockIdx.x, tid = threadIdx.x;
  size_t base = (size_t)row * D_MODEL;
  float v[3];
  float s = 0.f, sq = 0.f;
  for (int i = 0; i < 3; i++) {
    int c = tid + i * 256;
    size_t idx = base + c;
    float t = bf2f(p0[idx]) + bf2f(p1[idx]) + bf2f(p2[idx]) + bf2f(p3[idx])
            + x[idx] + bo[c];
    v[i] = t; yv[idx] = t;
    s += t; sq += t * t;
  }
  for (int m = 1; m < 64; m <<= 1) { s += __shfl_xor(s, m); sq += __shfl_xor(sq, m); }
  __shared__ float ss[4], ssq[4];
  int w = tid >> 6;
  if ((tid & 63) == 0) { ss[w] = s; ssq[w] = sq; }
  __syncthreads();
  s = ss[0] + ss[1] + ss[2] + ss[3];
  sq = ssq[0] + ssq[1] + ssq[2] + ssq[3];
  float mean = s * (1.f / D_MODEL);
  float var = sq * (1.f / D_MODEL) - mean * mean;
  float rstd = rsqrtf(var + 1e-5f);
  for (int i = 0; i < 3; i++) {
    int c = tid + i * 256;
    h2[base + c] = f2bf((v[i] - mean) * rstd * g[c] + be[c]);
  }
}

// ---- partial-sum(3, bf16) + residual + bias -> out fp32 (vectorized x4) ---
__global__ __launch_bounds__(256) void red_ff2(
    const u16* __restrict__ p0, const u16* __restrict__ p1,
    const u16* __restrict__ p2, const float* __restrict__ yv,
    const float* __restrict__ bias, float* __restrict__ out) {
  size_t i = ((size_t)blockIdx.x * 256 + threadIdx.x) * 4;
  int col = (int)(i % D_MODEL);
  ushort4 a = *(const ushort4*)(p0 + i);
  ushort4 b = *(const ushort4*)(p1 + i);
  ushort4 c = *(const ushort4*)(p2 + i);
  float4 y = *(const float4*)(yv + i);
  float4 o;
  o.x = bf2f(a.x) + bf2f(b.x) + bf2f(c.x) + y.x + bias[col];
  o.y = bf2f(a.y) + bf2f(b.y) + bf2f(c.y) + y.y + bias[col + 1];
  o.z = bf2f(a.z) + bf2f(b.z) + bf2f(c.z) + y.z + bias[col + 2];
  o.w = bf2f(a.w) + bf2f(b.w) + bf2f(c.w) + y.w + bias[col + 3];
  *(float4*)(out + i) = o;
}

// ---------------- GEMM: C[M][N] = A[M][K](bf16) * Bt[N][K](bf16)^T ---------
template <int EPI>
__global__ __launch_bounds__(256) void gemm_bt(
    const u16* __restrict__ A, const u16* __restrict__ Bt,
    int M, int N, int K,
    u16* __restrict__ outb, const float* __restrict__ bias,
    float qs, int qn,
    u16* __restrict__ p0, u16* __restrict__ p1,
    u16* __restrict__ p2, u16* __restrict__ p3) {
  __shared__ __align__(16) u16 lA[128 * 32];
  __shared__ __align__(16) u16 lB[128 * 32];
  const int tid = threadIdx.x;
  const int lane = tid & 63, w = tid >> 6;
  const int quad = lane >> 4, l15 = lane & 15;
  const int wm = w >> 1, wn = w & 1;
  const int bm = blockIdx.y, bn = blockIdx.x;
  const int Ksub = K / gridDim.z;
  const int k0 = blockIdx.z * Ksub;

  fx4 acc[4][4] = {};

  for (int kt = k0; kt < k0 + Ksub; kt += 32) {
    __syncthreads();
    for (int t = 0; t < 2; t++) {
      int p = (w * 2 + t) * 64 + lane;
      int m = p >> 2, qp = p & 3;
      int ql = qp ^ ((m >> 1) & 3);
      async16(A + (size_t)(bm * 128 + m) * K + kt + ql * 8,
              (char*)lA + (w * 2 + t) * 1024);
    }
    for (int t = 0; t < 2; t++) {
      int p = (w * 2 + t) * 64 + lane;
      int n = p >> 2, qp = p & 3;
      int ql = qp ^ ((n >> 1) & 3);
      async16(Bt + (size_t)(bn * 128 + n) * K + kt + ql * 8,
              (char*)lB + (w * 2 + t) * 1024);
    }
    __syncthreads();
    s16x8 af[4], bfr[4];
    for (int i = 0; i < 4; i++) {
      int m = wm * 64 + i * 16 + l15;
      int phys = m * 4 + (quad ^ ((m >> 1) & 3));
      af[i] = *(const s16x8*)((const char*)lA + phys * 16);
    }
    for (int j = 0; j < 4; j++) {
      int n = wn * 64 + j * 16 + l15;
      int phys = n * 4 + (quad ^ ((n >> 1) & 3));
      bfr[j] = *(const s16x8*)((const char*)lB + phys * 16);
    }
    for (int i = 0; i < 4; i++)
      for (int j = 0; j < 4; j++)
        acc[i][j] = __builtin_amdgcn_mfma_f32_16x16x32_bf16(af[i], bfr[j], acc[i][j], 0, 0, 0);
  }

  u16* pb = nullptr;
  if (EPI == 3)
    pb = blockIdx.z == 0 ? p0 : blockIdx.z == 1 ? p1 : blockIdx.z == 2 ? p2 : p3;

  for (int i = 0; i < 4; i++)
    for (int j = 0; j < 4; j++)
      for (int r = 0; r < 4; r++) {
        int row = bm * 128 + wm * 64 + i * 16 + quad * 4 + r;
        int col = bn * 128 + wn * 64 + j * 16 + l15;
        float v = acc[i][j][r];
        if (EPI == 0) {
          float vv = (col < qn) ? v * qs : v;
          outb[(size_t)row * N + col] = f2bf(vv);
        } else if (EPI == 2) {
          outb[(size_t)row * N + col] = f2bf(fmaxf(v + bias[col], 0.f));
        } else {
          pb[(size_t)row * N + col] = f2bf(v);
        }
      }
}

// ---------------- Flash attention, S^T form, split over keys ---------------
// grid (qt=32, bh=24, sp=2). Block: 64 q-rows x 1024 keys (16 iters of 64).
// Wave w owns q-slice w*16..w*16+15 (q = l15 in all fragments).
// S^T[key][q] via mfma_16x16x16: C-frag(row=key=quad*4+r, col=q=l15) is
// directly the B-frag (k=quad*4+j, n=l15) for O^T = V^T.P^T. No P LDS trip.
__global__ __launch_bounds__(256) void attn_kernel(
    const u16* __restrict__ qkv, const u16* __restrict__ vt,
    const float* __restrict__ maskadd,
    u16* __restrict__ pO0, u16* __restrict__ pO1, float* __restrict__ pL) {
  __shared__ __align__(16) u16 sQ[64 * 64];
  __shared__ __align__(16) u16 sK[64 * 64];
  __shared__ __align__(16) u16 sV[64 * 64];
  __shared__ __align__(16) float smask[1024];
  const int bh = blockIdx.y, b = bh / NH, h = bh % NH;
  const int qt = blockIdx.x, sp = blockIdx.z;
  const int tid = threadIdx.x, lane = tid & 63, w = tid >> 6;
  const int quad = lane >> 4, l15 = lane & 15;

  // stage Q tile (64x64), chunk swizzle q ^ (m&7)
  for (int t = 0; t < 2; t++) {
    int p = (w * 2 + t) * 64 + lane;
    int m = p >> 3, qp = p & 7, ql = qp ^ (m & 7);
    async16(qkv + (size_t)(b * TT + qt * 64 + m) * 2304 + h * HS + ql * 8,
            (char*)sQ + (w * 2 + t) * 1024);
  }
  // stage this split's mask slice
  for (int j = 0; j < 4; j++)
    smask[tid + j * 256] = maskadd[b * TT + sp * 1024 + tid + j * 256];
  __syncthreads();

  // preload Q B-frags: B[k=hs][n=q], lane q = w*16+l15, k = ks*16+quad*4+j
  s16x4 qb[4];
  for (int ks = 0; ks < 4; ks++)
    qb[ks] = lds_rd64(sQ, w * 16 + l15, ks * 4 + quad);

  float lsum = 0.f;       // per-lane: q = l15, key-quad = quad
  fx4 o[4] = {};          // O^T: row vd = jv*16+quad*4+r, col q = l15

  for (int kc = 0; kc < 16; kc++) {
    int key0 = sp * 1024 + kc * 64;
    __syncthreads();
    for (int t = 0; t < 2; t++) {  // K chunk: 64 keys x 64 hs
      int p = (w * 2 + t) * 64 + lane;
      int m = p >> 3, qp = p & 7, ql = qp ^ (m & 7);
      async16(qkv + (size_t)(b * TT + key0 + m) * 2304 + D_MODEL + h * HS + ql * 8,
              (char*)sK + (w * 2 + t) * 1024);
    }
    for (int t = 0; t < 2; t++) {  // V^T chunk: 64 vd x 64 keys
      int p = (w * 2 + t) * 64 + lane;
      int m = p >> 3, qp = p & 7, ql = qp ^ (m & 7);
      async16(vt + (size_t)bh * HS * TT + (size_t)m * TT + key0 + ql * 8,
              (char*)sV + (w * 2 + t) * 1024);
    }
    __syncthreads();

    for (int kt = 0; kt < 4; kt++) {
      // C-init = mask bias for keys kt*16+quad*4 .. +3 (broadcast per quad)
      float4 mb = *(const float4*)&smask[kc * 64 + kt * 16 + quad * 4];
      fx4 s = {mb.x, mb.y, mb.z, mb.w};
      for (int ks = 0; ks < 4; ks++) {
        s16x4 ak = lds_rd64(sK, kt * 16 + l15, ks * 4 + quad);
        s = __builtin_amdgcn_mfma_f32_16x16x16bf16_1k(ak, qb[ks], s, 0, 0, 0);
      }
      float e0 = __builtin_amdgcn_exp2f(s[0]);
      float e1 = __builtin_amdgcn_exp2f(s[1]);
      float e2 = __builtin_amdgcn_exp2f(s[2]);
      float e3 = __builtin_amdgcn_exp2f(s[3]);
      lsum += (e0 + e1) + (e2 + e3);
      s16x4 pB = pack4(e0, e1, e2, e3);   // P^T B-frag, directly from C-frag
      for (int jv = 0; jv < 4; jv++) {
        s16x4 av = lds_rd64(sV, jv * 16 + l15, kt * 4 + quad);
        o[jv] = __builtin_amdgcn_mfma_f32_16x16x16bf16_1k(av, pB, o[jv], 0, 0, 0);
      }
    }
  }

  // total lsum per q: reduce over key-quads
  lsum += __shfl_xor(lsum, 16);
  lsum += __shfl_xor(lsum, 32);

  const int tile = bh * 32 + qt;
  u16* po = sp ? pO1 : pO0;
  size_t base = (size_t)tile * 4096;
  for (int jv = 0; jv < 4; jv++)
    for (int r = 0; r < 4; r++) {
      int vd = jv * 16 + quad * 4 + r;
      po[base + vd * 64 + w * 16 + l15] = f2bf(o[jv][r]);
    }
  if (quad == 0) pL[sp * 49152 + tile * 64 + w * 16 + l15] = lsum;
}

// ---- combine 2 key-splits: out[tok][hd] = (pO0+pO1)[vd][q] / (l0+l1)[q] ---
__global__ __launch_bounds__(256) void attn_reduce(
    const u16* __restrict__ pO0, const u16* __restrict__ pO1,
    const float* __restrict__ pL, u16* __restrict__ out) {
  __shared__ float T[64 * 65];
  __shared__ float rinv[64];
  const int tile = blockIdx.x;            // bh*32 + qt
  const int bh = tile >> 5, qt = tile & 31, b = bh / NH, h = bh % NH;
  const int t = threadIdx.x;
  if (t < 64) rinv[t] = 1.f / (pL[tile * 64 + t] + pL[49152 + tile * 64 + t]);
  __syncthreads();
  size_t base = (size_t)tile * 4096;
  for (int i = 0; i < 16; i++) {
    int idx = i * 256 + t, vd = idx >> 6, q = idx & 63;
    T[vd * 65 + q] = (bf2f(pO0[base + idx]) + bf2f(pO1[base + idx])) * rinv[q];
  }
  __syncthreads();
  int q = t >> 2, vb = (t & 3) * 16;
  u16* orow = out + (size_t)(b * TT + qt * 64 + q) * D_MODEL + h * HS + vb;
  for (int i = 0; i < 8; i++) {
    int vd = vb + i * 2;
    u32 pk = (u32)f2bf(T[vd * 65 + q]) | ((u32)f2bf(T[(vd + 1) * 65 + q]) << 16);
    *(u32*)(orow + i * 2) = pk;
  }
}

extern "C" void kernel_launch(void* const* d_in, const int* in_sizes, int n_in,
                              void* d_out, int out_size, void* d_ws, size_t ws_size,
                              hipStream_t stream) {
  const float* x    = (const float*)d_in[0];
  const int*   mask = (const int*)d_in[1];
  const float* Wq   = (const float*)d_in[2];
  const float* Wk   = (const float*)d_in[3];
  const float* Wv   = (const float*)d_in[4];
  const float* Wo   = (const float*)d_in[5];
  const float* bo   = (const float*)d_in[6];
  const float* g1   = (const float*)d_in[7];
  const float* be1  = (const float*)d_in[8];
  const float* g2   = (const float*)d_in[9];
  const float* be2  = (const float*)d_in[10];
  const float* W1   = (const float*)d_in[11];
  const float* bb1  = (const float*)d_in[12];
  const float* W2   = (const float*)d_in[13];
  const float* bb2  = (const float*)d_in[14];
  float* out = (float*)d_out;
  char* ws = (char*)d_ws;

  // workspace carve (bytes), total 64,503,808
  u16*   WqkvT = (u16*)(ws + 0);           //  3,538,944  [2304][768]
  u16*   WoT   = (u16*)(ws + 3538944);     //  1,179,648  [768][768]
  u16*   W1T   = (u16*)(ws + 4718592);     //  4,718,592  [3072][768]
  u16*   W2T   = (u16*)(ws + 9437184);     //  4,718,592  [768][3072]
  u16*   h1    = (u16*)(ws + 14155776);    //  6,291,456  [4096][768]; h2/pO0 alias
  u16*   QKV   = (u16*)(ws + 20447232);    // 18,874,368  [4096][2304]
  u16*   Vt    = (u16*)(ws + 39321600);    //  6,291,456  [24][64][2048]
  u16*   attn  = (u16*)(ws + 45613056);    //  6,291,456  [4096][768]
  float* yv    = (float*)(ws + 51904512);  // 12,582,912  [4096][768]
  float* mbias = yv;                       // 16,384 B; dead before Wo writes yv
  u16*   pO0   = h1;                       // attn partial split 0 (h1 dead)
  u16*   pO1   = (u16*)(ws + 51920896);    // 6,291,456 inside yv after mbias
  float* pL    = (float*)(ws + 58212352);  // 393,216  [2][768][64]
  u16*   h2    = h1;
  u16*   ff1   = QKV;                      // 25,165,824 spans QKV+Vt
  // Wo partials (4 x 6,291,456): QKV+Vt span (dead after attn)
  u16* pw0 = (u16*)(ws + 20447232);
  u16* pw1 = (u16*)(ws + 26738688);
  u16* pw2 = (u16*)(ws + 33030144);
  u16* pw3 = (u16*)(ws + 39321600);
  // FF2 partials (3 x 6,291,456)
  u16* pf0 = (u16*)(ws + 0);               // weight-head region (dead)
  u16* pf1 = (u16*)(ws + 14155776);        // h2 (dead after FF1)
  u16* pf2 = (u16*)(ws + 45613056);        // attn (dead after Wo)

  const float QS = 0.05205875399f;  // 768^-0.5 * log2(e)

  dim3 tb(32, 8);
  tconv3<<<dim3(24, 24, 3), tb, 0, stream>>>(Wq, Wk, Wv, WqkvT);
  tconv<<<dim3(24, 24), tb, 0, stream>>>(Wo, WoT, 768, 768);
  tconv<<<dim3(96, 24), tb, 0, stream>>>(W1, W1T, 768, 3072);
  tconv<<<dim3(24, 96), tb, 0, stream>>>(W2, W2T, 3072, 768);
  maskbias<<<16, 256, 0, stream>>>(mask, mbias);

  ln_kernel<<<4096, 256, 0, stream>>>(x, g1, be1, h1);
  gemm_bt<0><<<dim3(18, 32, 1), 256, 0, stream>>>(h1, WqkvT, 4096, 2304, 768,
      QKV, nullptr, QS, 768, nullptr, nullptr, nullptr, nullptr);
  vt_extract<<<dim3(64, 2, 24), tb, 0, stream>>>(QKV, Vt);
  attn_kernel<<<dim3(32, 24, 2), 256, 0, stream>>>(QKV, Vt, mbias, pO0, pO1, pL);
  attn_reduce<<<768, 256, 0, stream>>>(pO0, pO1, pL, attn);
  // Wo: split-K=4 -> 768 blocks (3/CU)
  gemm_bt<3><<<dim3(6, 32, 4), 256, 0, stream>>>(attn, WoT, 4096, 768, 768,
      nullptr, nullptr, 1.f, 0, pw0, pw1, pw2, pw3);
  red_wo_ln<<<4096, 256, 0, stream>>>(pw0, pw1, pw2, pw3, x, bo, g2, be2, yv, h2);
  gemm_bt<2><<<dim3(24, 32, 1), 256, 0, stream>>>(h2, W1T, 4096, 3072, 768,
      ff1, bb1, 1.f, 0, nullptr, nullptr, nullptr, nullptr);
  // FF2: split-K=3 -> 576 blocks (2.25/CU)
  gemm_bt<3><<<dim3(6, 32, 3), 256, 0, stream>>>(ff1, W2T, 4096, 768, 3072,
      nullptr, nullptr, 1.f, 0, pf0, pf1, pf2, nullptr);
  red_ff2<<<3072, 256, 0, stream>>>(pf0, pf1, pf2, yv, bb2, out);
}

// Round 5
// 301.776 us; speedup vs baseline: 1.0728x; 1.0728x over previous
//
#include <hip/hip_runtime.h>
#include <hip/hip_bf16.h>

// Transformer block: x[2,2048,768] fp32. All GEMMs in bf16 MFMA (16x16x32),
// fp32 accumulate. N=768 GEMMs (Wo, FF2) use split-K with bf16 partials.
// Attention v3: S^T = K.Q^T via 16x16x32 (b128 conflict-free LDS reads);
// P^T C-frag is directly the B-frag of O^T = V^T.P^T via 16x16x16 (shape-
// independent C layout); V in padded-row LDS (136B) staged via registers ->
// conflict-free b64 A-frag reads with immediate-folded addressing.

typedef unsigned short u16;
typedef unsigned int u32;
typedef __attribute__((ext_vector_type(8))) short s16x8;   // 8 bf16 (4 VGPR)
typedef __attribute__((ext_vector_type(4))) short s16x4;   // 4 bf16 (2 VGPR)
typedef __attribute__((ext_vector_type(4))) float fx4;     // 4 fp32 acc

#define D_MODEL 768
#define NH 12
#define HS 64
#define TT 2048
#define BB 2

__device__ __forceinline__ u16 f2bf(float f) {
  union { float f; u32 u; } v; v.f = f;
  u32 r = v.u + 0x7fffu + ((v.u >> 16) & 1u);   // RNE
  return (u16)(r >> 16);
}
__device__ __forceinline__ float bf2f(u16 h) {
  union { u32 u; float f; } v; v.u = ((u32)h) << 16; return v.f;
}
__device__ __forceinline__ s16x4 pack4(float a, float b, float c, float d) {
  union { __hip_bfloat162 h2[2]; s16x4 v; } u;
  u.h2[0] = __float22bfloat162_rn({a, b});
  u.h2[1] = __float22bfloat162_rn({c, d});
  return u.v;
}

// async global->LDS, 16B per lane; LDS dest = wave-uniform base + lane*16
__device__ __forceinline__ void async16(const void* g, void* l) {
  __builtin_amdgcn_global_load_lds(
      (const __attribute__((address_space(1))) u32*)g,
      (__attribute__((address_space(3))) u32*)l, 16, 0, 0);
}

// ---------------- transpose + fp32->bf16 convert: in[R][C] -> out[C][R] ----
__global__ __launch_bounds__(256) void tconv(const float* __restrict__ in,
                                             u16* __restrict__ out, int R, int C) {
  __shared__ float t[32][33];
  int c0 = blockIdx.x * 32, r0 = blockIdx.y * 32;
  int x = threadIdx.x, y = threadIdx.y;
  for (int i = 0; i < 4; i++)
    t[y + i * 8][x] = in[(size_t)(r0 + y + i * 8) * C + c0 + x];
  __syncthreads();
  for (int i = 0; i < 4; i++)
    out[(size_t)(c0 + y + i * 8) * R + r0 + x] = f2bf(t[x][y + i * 8]);
}

// three 768x768 transposes in one launch (z selects Wq/Wk/Wv)
__global__ __launch_bounds__(256) void tconv3(const float* __restrict__ w0,
                                              const float* __restrict__ w1,
                                              const float* __restrict__ w2,
                                              u16* __restrict__ out) {
  __shared__ float t[32][33];
  const float* in = blockIdx.z == 0 ? w0 : blockIdx.z == 1 ? w1 : w2;
  u16* o = out + (size_t)blockIdx.z * 768 * 768;
  int c0 = blockIdx.x * 32, r0 = blockIdx.y * 32;
  int x = threadIdx.x, y = threadIdx.y;
  for (int i = 0; i < 4; i++)
    t[y + i * 8][x] = in[(size_t)(r0 + y + i * 8) * 768 + c0 + x];
  __syncthreads();
  for (int i = 0; i < 4; i++)
    o[(size_t)(c0 + y + i * 8) * 768 + r0 + x] = f2bf(t[x][y + i * 8]);
}

// ---------------- V^T extraction: QKV[4096][2304] -> Vt[24][64][2048] ------
__global__ __launch_bounds__(256) void vt_extract(const u16* __restrict__ qkv,
                                                  u16* __restrict__ vt) {
  __shared__ u16 t[32][33];
  int bh = blockIdx.z, b = bh / NH, h = bh % NH;
  int t0 = blockIdx.x * 32, v0 = blockIdx.y * 32;
  int x = threadIdx.x, y = threadIdx.y;
  for (int i = 0; i < 4; i++)
    t[y + i * 8][x] = qkv[(size_t)(b * TT + t0 + y + i * 8) * 2304 + 1536 + h * HS + v0 + x];
  __syncthreads();
  for (int i = 0; i < 4; i++)
    vt[(size_t)(bh * HS + v0 + y + i * 8) * TT + t0 + x] = t[x][y + i * 8];
}

// ---------------- mask -> additive bias (log2 domain) ----------------------
__global__ __launch_bounds__(256) void maskbias(const int* __restrict__ mask,
                                                float* __restrict__ mb) {
  int i = blockIdx.x * 256 + threadIdx.x;
  mb[i] = mask[i] ? 0.f : -1e30f;
}

// ---------------- LayerNorm: fp32 row[768] -> bf16 ------------------------
__global__ __launch_bounds__(256) void ln_kernel(const float* __restrict__ x,
                                                 const float* __restrict__ g,
                                                 const float* __restrict__ bta,
                                                 u16* __restrict__ out) {
  int row = blockIdx.x;
  const float* xr = x + (size_t)row * D_MODEL;
  int tid = threadIdx.x;
  float v0 = xr[tid], v1 = xr[tid + 256], v2 = xr[tid + 512];
  float s = v0 + v1 + v2, sq = v0 * v0 + v1 * v1 + v2 * v2;
  for (int m = 1; m < 64; m <<= 1) { s += __shfl_xor(s, m); sq += __shfl_xor(sq, m); }
  __shared__ float ss[4], ssq[4];
  int w = tid >> 6;
  if ((tid & 63) == 0) { ss[w] = s; ssq[w] = sq; }
  __syncthreads();
  s = ss[0] + ss[1] + ss[2] + ss[3];
  sq = ssq[0] + ssq[1] + ssq[2] + ssq[3];
  float mean = s * (1.f / D_MODEL);
  float var = sq * (1.f / D_MODEL) - mean * mean;
  float rstd = rsqrtf(var + 1e-5f);
  u16* orow = out + (size_t)row * D_MODEL;
  orow[tid]       = f2bf((v0 - mean) * rstd * g[tid]       + bta[tid]);
  orow[tid + 256] = f2bf((v1 - mean) * rstd * g[tid + 256] + bta[tid + 256]);
  orow[tid + 512] = f2bf((v2 - mean) * rstd * g[tid + 512] + bta[tid + 512]);
}

// ---- partial-sum(4, bf16) + residual + bias + LayerNorm -> yv fp32, h2 bf16
__global__ __launch_bounds__(256) void red_wo_ln(
    const u16* __restrict__ p0, const u16* __restrict__ p1,
    const u16* __restrict__ p2, const u16* __restrict__ p3,
    const float* __restrict__ x, const float* __restrict__ bo,
    const float* __restrict__ g, const float* __restrict__ be,
    float* __restrict__ yv, u16* __restrict__ h2) {
  int row = blockIdx.x, tid = threadIdx.x;
  size_t base = (size_t)row * D_MODEL;
  float v[3];
  float s = 0.f, sq = 0.f;
  for (int i = 0; i < 3; i++) {
    int c = tid + i * 256;
    size_t idx = base + c;
    float t = bf2f(p0[idx]) + bf2f(p1[idx]) + bf2f(p2[idx]) + bf2f(p3[idx])
            + x[idx] + bo[c];
    v[i] = t; yv[idx] = t;
    s += t; sq += t * t;
  }
  for (int m = 1; m < 64; m <<= 1) { s += __shfl_xor(s, m); sq += __shfl_xor(sq, m); }
  __shared__ float ss[4], ssq[4];
  int w = tid >> 6;
  if ((tid & 63) == 0) { ss[w] = s; ssq[w] = sq; }
  __syncthreads();
  s = ss[0] + ss[1] + ss[2] + ss[3];
  sq = ssq[0] + ssq[1] + ssq[2] + ssq[3];
  float mean = s * (1.f / D_MODEL);
  float var = sq * (1.f / D_MODEL) - mean * mean;
  float rstd = rsqrtf(var + 1e-5f);
  for (int i = 0; i < 3; i++) {
    int c = tid + i * 256;
    h2[base + c] = f2bf((v[i] - mean) * rstd * g[c] + be[c]);
  }
}

// ---- partial-sum(3, bf16) + residual + bias -> out fp32 (vectorized x4) ---
__global__ __launch_bounds__(256) void red_ff2(
    const u16* __restrict__ p0, const u16* __restrict__ p1,
    const u16* __restrict__ p2, const float* __restrict__ yv,
    const float* __restrict__ bias, float* __restrict__ out) {
  size_t i = ((size_t)blockIdx.x * 256 + threadIdx.x) * 4;
  int col = (int)(i % D_MODEL);
  ushort4 a = *(const ushort4*)(p0 + i);
  ushort4 b = *(const ushort4*)(p1 + i);
  ushort4 c = *(const ushort4*)(p2 + i);
  float4 y = *(const float4*)(yv + i);
  float4 o;
  o.x = bf2f(a.x) + bf2f(b.x) + bf2f(c.x) + y.x + bias[col];
  o.y = bf2f(a.y) + bf2f(b.y) + bf2f(c.y) + y.y + bias[col + 1];
  o.z = bf2f(a.z) + bf2f(b.z) + bf2f(c.z) + y.z + bias[col + 2];
  o.w = bf2f(a.w) + bf2f(b.w) + bf2f(c.w) + y.w + bias[col + 3];
  *(float4*)(out + i) = o;
}

// ---------------- GEMM: C[M][N] = A[M][K](bf16) * Bt[N][K](bf16)^T ---------
template <int EPI>
__global__ __launch_bounds__(256) void gemm_bt(
    const u16* __restrict__ A, const u16* __restrict__ Bt,
    int M, int N, int K,
    u16* __restrict__ outb, const float* __restrict__ bias,
    float qs, int qn,
    u16* __restrict__ p0, u16* __restrict__ p1,
    u16* __restrict__ p2, u16* __restrict__ p3) {
  __shared__ __align__(16) u16 lA[128 * 32];
  __shared__ __align__(16) u16 lB[128 * 32];
  const int tid = threadIdx.x;
  const int lane = tid & 63, w = tid >> 6;
  const int quad = lane >> 4, l15 = lane & 15;
  const int wm = w >> 1, wn = w & 1;
  const int bm = blockIdx.y, bn = blockIdx.x;
  const int Ksub = K / gridDim.z;
  const int k0 = blockIdx.z * Ksub;

  fx4 acc[4][4] = {};

  for (int kt = k0; kt < k0 + Ksub; kt += 32) {
    __syncthreads();
    for (int t = 0; t < 2; t++) {
      int p = (w * 2 + t) * 64 + lane;
      int m = p >> 2, qp = p & 3;
      int ql = qp ^ ((m >> 1) & 3);
      async16(A + (size_t)(bm * 128 + m) * K + kt + ql * 8,
              (char*)lA + (w * 2 + t) * 1024);
    }
    for (int t = 0; t < 2; t++) {
      int p = (w * 2 + t) * 64 + lane;
      int n = p >> 2, qp = p & 3;
      int ql = qp ^ ((n >> 1) & 3);
      async16(Bt + (size_t)(bn * 128 + n) * K + kt + ql * 8,
              (char*)lB + (w * 2 + t) * 1024);
    }
    __syncthreads();
    s16x8 af[4], bfr[4];
    for (int i = 0; i < 4; i++) {
      int m = wm * 64 + i * 16 + l15;
      int phys = m * 4 + (quad ^ ((m >> 1) & 3));
      af[i] = *(const s16x8*)((const char*)lA + phys * 16);
    }
    for (int j = 0; j < 4; j++) {
      int n = wn * 64 + j * 16 + l15;
      int phys = n * 4 + (quad ^ ((n >> 1) & 3));
      bfr[j] = *(const s16x8*)((const char*)lB + phys * 16);
    }
    for (int i = 0; i < 4; i++)
      for (int j = 0; j < 4; j++)
        acc[i][j] = __builtin_amdgcn_mfma_f32_16x16x32_bf16(af[i], bfr[j], acc[i][j], 0, 0, 0);
  }

  u16* pb = nullptr;
  if (EPI == 3)
    pb = blockIdx.z == 0 ? p0 : blockIdx.z == 1 ? p1 : blockIdx.z == 2 ? p2 : p3;

  for (int i = 0; i < 4; i++)
    for (int j = 0; j < 4; j++)
      for (int r = 0; r < 4; r++) {
        int row = bm * 128 + wm * 64 + i * 16 + quad * 4 + r;
        int col = bn * 128 + wn * 64 + j * 16 + l15;
        float v = acc[i][j][r];
        if (EPI == 0) {
          float vv = (col < qn) ? v * qs : v;
          outb[(size_t)row * N + col] = f2bf(vv);
        } else if (EPI == 2) {
          outb[(size_t)row * N + col] = f2bf(fmaxf(v + bias[col], 0.f));
        } else {
          pb[(size_t)row * N + col] = f2bf(v);
        }
      }
}

// ---------------- Flash attention v3 ---------------------------------------
// grid (qt=16, bh=24, sp=2), 512 threads (8 waves). Block: 128 q-rows x 1024
// keys (16 iters of 64). Wave w owns q-slice qt*128 + w*16 (q = l15).
// QK^T: S^T[key][q] via 16x16x32 (A=K rows b128, B=Q rows b128, swizzled,
// conflict-free). C-frag rows key=quad*4+r feed PV's 16x16x16 B-frag
// identity. V^T in padded LDS rows (136B) staged via registers: b64 A-frag
// reads are bank-conflict-free and kt/jv fold into ds_read immediates.
__global__ __launch_bounds__(512) void attn_kernel(
    const u16* __restrict__ qkv, const u16* __restrict__ vt,
    const float* __restrict__ maskadd,
    u16* __restrict__ pO0, u16* __restrict__ pO1, float* __restrict__ pL) {
  __shared__ __align__(16) u16 sQ[128 * 64];     // 16 KB, xor-swizzled chunks
  __shared__ __align__(16) u16 sK[64 * 64];      //  8 KB, xor-swizzled chunks
  __shared__ __align__(16) u16 sV[64 * 68];      //  8.5 KB, 136B padded rows
  __shared__ __align__(16) float smask[1024];
  const int bh = blockIdx.y, b = bh / NH, h = bh % NH;
  const int qt = blockIdx.x, sp = blockIdx.z;
  const int tid = threadIdx.x, lane = tid & 63, w = tid >> 6;
  const int quad = lane >> 4, l15 = lane & 15;

  // stage Q (128 rows x 64): 1024 chunks, swizzle qp ^ (row&7)
  for (int i = 0; i < 2; i++) {
    int p = i * 512 + tid;
    int m = p >> 3, qp = p & 7, ql = qp ^ (m & 7);
    async16(qkv + (size_t)(b * TT + qt * 128 + m) * 2304 + h * HS + ql * 8,
            (char*)sQ + i * 8192 + w * 1024);
  }
  smask[tid]       = maskadd[b * TT + sp * 1024 + tid];
  smask[tid + 512] = maskadd[b * TT + sp * 1024 + 512 + tid];
  // V prefetch for kc=0 (register staging)
  const u16* vbase = vt + (size_t)bh * HS * TT + (size_t)(tid >> 3) * TT + sp * 1024;
  s16x8 vcur = *(const s16x8*)(vbase + (tid & 7) * 8);
  __syncthreads();

  // Q B-frags: B[k=hs=quad*8+j][n=q], q-row = w*16 + l15, (row&7)==l15&7
  const int qrow = w * 16 + l15;
  s16x8 aq0 = *(const s16x8*)((const char*)sQ + qrow * 128 + ((quad ^ (l15 & 7)) * 16));
  s16x8 aq1 = *(const s16x8*)((const char*)sQ + qrow * 128 + (((4 + quad) ^ (l15 & 7)) * 16));

  // hoisted LDS bases (kt/jv become ds_read offset immediates)
  const char* pK0 = (const char*)sK + l15 * 128 + ((quad ^ (l15 & 7)) * 16);
  const char* pK1 = (const char*)sK + l15 * 128 + (((4 + quad) ^ (l15 & 7)) * 16);
  const char* pV  = (const char*)sV + l15 * 136 + quad * 8;
  char* vwr = (char*)sV + (tid >> 3) * 136 + (tid & 7) * 16;

  float lsum = 0.f;
  fx4 o[4] = {};

  for (int kc = 0; kc < 16; kc++) {
    __syncthreads();   // LDS safe to overwrite
    {  // stage K chunk (64 keys x 64 hs): 1 chunk/thread
      int m = tid >> 3, qp = tid & 7, ql = qp ^ (m & 7);
      async16(qkv + (size_t)(b * TT + sp * 1024 + kc * 64 + m) * 2304 + D_MODEL + h * HS + ql * 8,
              (char*)sK + w * 1024);
    }
    *(s16x8*)vwr = vcur;          // V tile (padded rows) from registers
    __syncthreads();
    int kn = (kc < 15) ? (kc + 1) * 64 : kc * 64;   // clamped prefetch
    s16x8 vnxt = *(const s16x8*)(vbase + kn + (tid & 7) * 8);

    #pragma unroll
    for (int kt = 0; kt < 4; kt++) {
      float4 mb = *(const float4*)&smask[kc * 64 + kt * 16 + quad * 4];
      fx4 s = {mb.x, mb.y, mb.z, mb.w};
      s16x8 ak0 = *(const s16x8*)(pK0 + kt * 2048);
      s16x8 ak1 = *(const s16x8*)(pK1 + kt * 2048);
      s = __builtin_amdgcn_mfma_f32_16x16x32_bf16(ak0, aq0, s, 0, 0, 0);
      s = __builtin_amdgcn_mfma_f32_16x16x32_bf16(ak1, aq1, s, 0, 0, 0);
      float e0 = __builtin_amdgcn_exp2f(s[0]);
      float e1 = __builtin_amdgcn_exp2f(s[1]);
      float e2 = __builtin_amdgcn_exp2f(s[2]);
      float e3 = __builtin_amdgcn_exp2f(s[3]);
      lsum += (e0 + e1) + (e2 + e3);
      s16x4 pB = pack4(e0, e1, e2, e3);   // P^T B-frag, straight from C-frag
      #pragma unroll
      for (int jv = 0; jv < 4; jv++) {
        s16x4 av = *(const s16x4*)(pV + jv * 2176 + kt * 32);
        o[jv] = __builtin_amdgcn_mfma_f32_16x16x16bf16_1k(av, pB, o[jv], 0, 0, 0);
      }
    }
    vcur = vnxt;
  }

  // lsum per q: reduce over key-quads
  lsum += __shfl_xor(lsum, 16);
  lsum += __shfl_xor(lsum, 32);

  const int tile = bh * 32 + qt * 2 + (w >> 2);   // 64-row output tile
  const int sub = (w & 3) * 16;
  u16* po = sp ? pO1 : pO0;
  size_t base = (size_t)tile * 4096;
  for (int jv = 0; jv < 4; jv++)
    for (int r = 0; r < 4; r++) {
      int vd = jv * 16 + quad * 4 + r;
      po[base + vd * 64 + sub + l15] = f2bf(o[jv][r]);
    }
  if (quad == 0) pL[sp * 49152 + tile * 64 + sub + l15] = lsum;
}

// ---- combine 2 key-splits: out[tok][hd] = (pO0+pO1)[vd][q] / (l0+l1)[q] ---
__global__ __launch_bounds__(256) void attn_reduce(
    const u16* __restrict__ pO0, const u16* __restrict__ pO1,
    const float* __restrict__ pL, u16* __restrict__ out) {
  __shared__ float T[64 * 65];
  __shared__ float rinv[64];
  const int tile = blockIdx.x;            // bh*32 + qt
  const int bh = tile >> 5, qt = tile & 31, b = bh / NH, h = bh % NH;
  const int t = threadIdx.x;
  if (t < 64) rinv[t] = 1.f / (pL[tile * 64 + t] + pL[49152 + tile * 64 + t]);
  __syncthreads();
  size_t base = (size_t)tile * 4096;
  for (int i = 0; i < 16; i++) {
    int idx = i * 256 + t, vd = idx >> 6, q = idx & 63;
    T[vd * 65 + q] = (bf2f(pO0[base + idx]) + bf2f(pO1[base + idx])) * rinv[q];
  }
  __syncthreads();
  int q = t >> 2, vb = (t & 3) * 16;
  u16* orow = out + (size_t)(b * TT + qt * 64 + q) * D_MODEL + h * HS + vb;
  for (int i = 0; i < 8; i++) {
    int vd = vb + i * 2;
    u32 pk = (u32)f2bf(T[vd * 65 + q]) | ((u32)f2bf(T[(vd + 1) * 65 + q]) << 16);
    *(u32*)(orow + i * 2) = pk;
  }
}

extern "C" void kernel_launch(void* const* d_in, const int* in_sizes, int n_in,
                              void* d_out, int out_size, void* d_ws, size_t ws_size,
                              hipStream_t stream) {
  const float* x    = (const float*)d_in[0];
  const int*   mask = (const int*)d_in[1];
  const float* Wq   = (const float*)d_in[2];
  const float* Wk   = (const float*)d_in[3];
  const float* Wv   = (const float*)d_in[4];
  const float* Wo   = (const float*)d_in[5];
  const float* bo   = (const float*)d_in[6];
  const float* g1   = (const float*)d_in[7];
  const float* be1  = (const float*)d_in[8];
  const float* g2   = (const float*)d_in[9];
  const float* be2  = (const float*)d_in[10];
  const float* W1   = (const float*)d_in[11];
  const float* bb1  = (const float*)d_in[12];
  const float* W2   = (const float*)d_in[13];
  const float* bb2  = (const float*)d_in[14];
  float* out = (float*)d_out;
  char* ws = (char*)d_ws;

  // workspace carve (bytes), total 64,503,808
  u16*   WqkvT = (u16*)(ws + 0);           //  3,538,944  [2304][768]
  u16*   WoT   = (u16*)(ws + 3538944);     //  1,179,648  [768][768]
  u16*   W1T   = (u16*)(ws + 4718592);     //  4,718,592  [3072][768]
  u16*   W2T   = (u16*)(ws + 9437184);     //  4,718,592  [768][3072]
  u16*   h1    = (u16*)(ws + 14155776);    //  6,291,456  [4096][768]; h2/pO0 alias
  u16*   QKV   = (u16*)(ws + 20447232);    // 18,874,368  [4096][2304]
  u16*   Vt    = (u16*)(ws + 39321600);    //  6,291,456  [24][64][2048]
  u16*   attn  = (u16*)(ws + 45613056);    //  6,291,456  [4096][768]
  float* yv    = (float*)(ws + 51904512);  // 12,582,912  [4096][768]
  float* mbias = yv;                       // 16,384 B; dead before Wo writes yv
  u16*   pO0   = h1;                       // attn partial split 0 (h1 dead)
  u16*   pO1   = (u16*)(ws + 51920896);    // 6,291,456 inside yv after mbias
  float* pL    = (float*)(ws + 58212352);  // 393,216  [2][768][64]
  u16*   h2    = h1;
  u16*   ff1   = QKV;                      // 25,165,824 spans QKV+Vt
  // Wo partials (4 x 6,291,456): QKV+Vt span (dead after attn)
  u16* pw0 = (u16*)(ws + 20447232);
  u16* pw1 = (u16*)(ws + 26738688);
  u16* pw2 = (u16*)(ws + 33030144);
  u16* pw3 = (u16*)(ws + 39321600);
  // FF2 partials (3 x 6,291,456)
  u16* pf0 = (u16*)(ws + 0);               // weight-head region (dead)
  u16* pf1 = (u16*)(ws + 14155776);        // h2 (dead after FF1)
  u16* pf2 = (u16*)(ws + 45613056);        // attn (dead after Wo)

  const float QS = 0.05205875399f;  // 768^-0.5 * log2(e)

  dim3 tb(32, 8);
  tconv3<<<dim3(24, 24, 3), tb, 0, stream>>>(Wq, Wk, Wv, WqkvT);
  tconv<<<dim3(24, 24), tb, 0, stream>>>(Wo, WoT, 768, 768);
  tconv<<<dim3(96, 24), tb, 0, stream>>>(W1, W1T, 768, 3072);
  tconv<<<dim3(24, 96), tb, 0, stream>>>(W2, W2T, 3072, 768);
  maskbias<<<16, 256, 0, stream>>>(mask, mbias);

  ln_kernel<<<4096, 256, 0, stream>>>(x, g1, be1, h1);
  gemm_bt<0><<<dim3(18, 32, 1), 256, 0, stream>>>(h1, WqkvT, 4096, 2304, 768,
      QKV, nullptr, QS, 768, nullptr, nullptr, nullptr, nullptr);
  vt_extract<<<dim3(64, 2, 24), tb, 0, stream>>>(QKV, Vt);
  attn_kernel<<<dim3(16, 24, 2), 512, 0, stream>>>(QKV, Vt, mbias, pO0, pO1, pL);
  attn_reduce<<<768, 256, 0, stream>>>(pO0, pO1, pL, attn);
  // Wo: split-K=4 -> 768 blocks (3/CU)
  gemm_bt<3><<<dim3(6, 32, 4), 256, 0, stream>>>(attn, WoT, 4096, 768, 768,
      nullptr, nullptr, 1.f, 0, pw0, pw1, pw2, pw3);
  red_wo_ln<<<4096, 256, 0, stream>>>(pw0, pw1, pw2, pw3, x, bo, g2, be2, yv, h2);
  gemm_bt<2><<<dim3(24, 32, 1), 256, 0, stream>>>(h2, W1T, 4096, 3072, 768,
      ff1, bb1, 1.f, 0, nullptr, nullptr, nullptr, nullptr);
  // FF2: split-K=3 -> 576 blocks (2.25/CU)
  gemm_bt<3><<<dim3(6, 32, 3), 256, 0, stream>>>(ff1, W2T, 4096, 768, 3072,
      nullptr, nullptr, 1.f, 0, pf0, pf1, pf2, nullptr);
  red_ff2<<<3072, 256, 0, stream>>>(pf0, pf1, pf2, yv, bb2, out);
}

// Round 6
// 277.434 us; speedup vs baseline: 1.1669x; 1.0877x over previous
//
#include <hip/hip_runtime.h>
#include <hip/hip_bf16.h>

// Transformer block: x[2,2048,768] fp32. All GEMMs bf16 MFMA 16x16x32,
// BK=64 (one barrier pair per 64 k), fp32 accumulate. N=768 GEMMs (Wo, FF2)
// split-K with bf16 partials. QKV epilogue writes V directly transposed.
// Attention: S^T = K.Q^T (16x16x32); P^T C-frag feeds O^T = V^T.P^T B-frag
// (16x16x16 identity); fixed-shift softmax in log2 domain, split over keys.

typedef unsigned short u16;
typedef unsigned int u32;
typedef __attribute__((ext_vector_type(8))) short s16x8;   // 8 bf16 (4 VGPR)
typedef __attribute__((ext_vector_type(4))) short s16x4;   // 4 bf16 (2 VGPR)
typedef __attribute__((ext_vector_type(4))) float fx4;     // 4 fp32 acc

#define D_MODEL 768
#define NH 12
#define HS 64
#define TT 2048
#define BB 2

__device__ __forceinline__ u16 f2bf(float f) {
  union { float f; u32 u; } v; v.f = f;
  u32 r = v.u + 0x7fffu + ((v.u >> 16) & 1u);   // RNE
  return (u16)(r >> 16);
}
__device__ __forceinline__ float bf2f(u16 h) {
  union { u32 u; float f; } v; v.u = ((u32)h) << 16; return v.f;
}
__device__ __forceinline__ s16x4 pack4(float a, float b, float c, float d) {
  union { __hip_bfloat162 h2[2]; s16x4 v; } u;
  u.h2[0] = __float22bfloat162_rn({a, b});
  u.h2[1] = __float22bfloat162_rn({c, d});
  return u.v;
}

// async global->LDS, 16B per lane; LDS dest = wave-uniform base + lane*16
__device__ __forceinline__ void async16(const void* g, void* l) {
  __builtin_amdgcn_global_load_lds(
      (const __attribute__((address_space(1))) u32*)g,
      (__attribute__((address_space(3))) u32*)l, 16, 0, 0);
}

// ---------------- mega preprocessing kernel --------------------------------
// blocks [0,6912): weight transpose+convert tiles (Wq,Wk,Wv,Wo,W1,W2)
// blocks [6912,11008): LayerNorm1 rows      blocks [11008,11024): mask bias
__global__ __launch_bounds__(256) void preproc(
    const float* __restrict__ x, const int* __restrict__ mask,
    const float* __restrict__ Wq, const float* __restrict__ Wk,
    const float* __restrict__ Wv, const float* __restrict__ Wo,
    const float* __restrict__ W1, const float* __restrict__ W2,
    const float* __restrict__ g1, const float* __restrict__ be1,
    u16* __restrict__ WqkvT, u16* __restrict__ WoT,
    u16* __restrict__ W1T, u16* __restrict__ W2T,
    u16* __restrict__ h1, float* __restrict__ mb) {
  __shared__ float t[32][33];
  __shared__ float ss[4], ssq[4];
  const int bid = blockIdx.x, tid = threadIdx.x;
  if (bid < 6912) {
    const float* in; u16* out; int R, C, cx, cy;
    if (bid < 1728) {
      int wsel = bid / 576, s = bid % 576;
      in = wsel == 0 ? Wq : wsel == 1 ? Wk : Wv;
      out = WqkvT + (size_t)wsel * 768 * 768;
      R = 768; C = 768; cx = s % 24; cy = s / 24;
    } else if (bid < 2304) {
      int s = bid - 1728; in = Wo; out = WoT;
      R = 768; C = 768; cx = s % 24; cy = s / 24;
    } else if (bid < 4608) {
      int s = bid - 2304; in = W1; out = W1T;
      R = 768; C = 3072; cx = s % 96; cy = s / 96;
    } else {
      int s = bid - 4608; in = W2; out = W2T;
      R = 3072; C = 768; cx = s % 24; cy = s / 24;
    }
    int c0 = cx * 32, r0 = cy * 32, xx = tid & 31, yy = tid >> 5;
    for (int i = 0; i < 4; i++)
      t[yy + i * 8][xx] = in[(size_t)(r0 + yy + i * 8) * C + c0 + xx];
    __syncthreads();
    for (int i = 0; i < 4; i++)
      out[(size_t)(c0 + yy + i * 8) * R + r0 + xx] = f2bf(t[xx][yy + i * 8]);
  } else if (bid < 11008) {
    int row = bid - 6912;
    const float* xr = x + (size_t)row * D_MODEL;
    float v0 = xr[tid], v1 = xr[tid + 256], v2 = xr[tid + 512];
    float s = v0 + v1 + v2, sq = v0 * v0 + v1 * v1 + v2 * v2;
    for (int m = 1; m < 64; m <<= 1) { s += __shfl_xor(s, m); sq += __shfl_xor(sq, m); }
    int w = tid >> 6;
    if ((tid & 63) == 0) { ss[w] = s; ssq[w] = sq; }
    __syncthreads();
    s = ss[0] + ss[1] + ss[2] + ss[3];
    sq = ssq[0] + ssq[1] + ssq[2] + ssq[3];
    float mean = s * (1.f / D_MODEL);
    float var = sq * (1.f / D_MODEL) - mean * mean;
    float rstd = rsqrtf(var + 1e-5f);
    u16* orow = h1 + (size_t)row * D_MODEL;
    orow[tid]       = f2bf((v0 - mean) * rstd * g1[tid]       + be1[tid]);
    orow[tid + 256] = f2bf((v1 - mean) * rstd * g1[tid + 256] + be1[tid + 256]);
    orow[tid + 512] = f2bf((v2 - mean) * rstd * g1[tid + 512] + be1[tid + 512]);
  } else {
    int i = (bid - 11008) * 256 + tid;
    mb[i] = mask[i] ? 0.f : -1e30f;
  }
}

// ---- partial-sum(4, bf16) + residual + bias + LayerNorm -> yv fp32, h2 bf16
__global__ __launch_bounds__(256) void red_wo_ln(
    const u16* __restrict__ p0, const u16* __restrict__ p1,
    const u16* __restrict__ p2, const u16* __restrict__ p3,
    const float* __restrict__ x, const float* __restrict__ bo,
    const float* __restrict__ g, const float* __restrict__ be,
    float* __restrict__ yv, u16* __restrict__ h2) {
  int row = blockIdx.x, tid = threadIdx.x;
  size_t base = (size_t)row * D_MODEL;
  float v[3];
  float s = 0.f, sq = 0.f;
  for (int i = 0; i < 3; i++) {
    int c = tid + i * 256;
    size_t idx = base + c;
    float t = bf2f(p0[idx]) + bf2f(p1[idx]) + bf2f(p2[idx]) + bf2f(p3[idx])
            + x[idx] + bo[c];
    v[i] = t; yv[idx] = t;
    s += t; sq += t * t;
  }
  for (int m = 1; m < 64; m <<= 1) { s += __shfl_xor(s, m); sq += __shfl_xor(sq, m); }
  __shared__ float ss[4], ssq[4];
  int w = tid >> 6;
  if ((tid & 63) == 0) { ss[w] = s; ssq[w] = sq; }
  __syncthreads();
  s = ss[0] + ss[1] + ss[2] + ss[3];
  sq = ssq[0] + ssq[1] + ssq[2] + ssq[3];
  float mean = s * (1.f / D_MODEL);
  float var = sq * (1.f / D_MODEL) - mean * mean;
  float rstd = rsqrtf(var + 1e-5f);
  for (int i = 0; i < 3; i++) {
    int c = tid + i * 256;
    h2[base + c] = f2bf((v[i] - mean) * rstd * g[c] + be[c]);
  }
}

// ---- partial-sum(3, bf16) + residual + bias -> out fp32 (vectorized x4) ---
__global__ __launch_bounds__(256) void red_ff2(
    const u16* __restrict__ p0, const u16* __restrict__ p1,
    const u16* __restrict__ p2, const float* __restrict__ yv,
    const float* __restrict__ bias, float* __restrict__ out) {
  size_t i = ((size_t)blockIdx.x * 256 + threadIdx.x) * 4;
  int col = (int)(i % D_MODEL);
  ushort4 a = *(const ushort4*)(p0 + i);
  ushort4 b = *(const ushort4*)(p1 + i);
  ushort4 c = *(const ushort4*)(p2 + i);
  float4 y = *(const float4*)(yv + i);
  float4 o;
  o.x = bf2f(a.x) + bf2f(b.x) + bf2f(c.x) + y.x + bias[col];
  o.y = bf2f(a.y) + bf2f(b.y) + bf2f(c.y) + y.y + bias[col + 1];
  o.z = bf2f(a.z) + bf2f(b.z) + bf2f(c.z) + y.z + bias[col + 2];
  o.w = bf2f(a.w) + bf2f(b.w) + bf2f(c.w) + y.w + bias[col + 3];
  *(float4*)(out + i) = o;
}

// ---------------- GEMM: C[M][N] = A[M][K](bf16) * Bt[N][K](bf16)^T ---------
// 128x128 tile, BK=64 (32 MFMA per barrier pair), 4 waves 2x2, 4x4 tiles.
// Split-K via gridDim.z. EPI 0: bf16 out, cols<768 scaled by qs; if vtp set,
// cols>=1536 (V region) go transposed to vtp instead. EPI 2: relu(acc+bias).
// EPI 3: bf16 partial -> p[blockIdx.z].
template <int EPI>
__global__ __launch_bounds__(256) void gemm_bt(
    const u16* __restrict__ A, const u16* __restrict__ Bt,
    int M, int N, int K,
    u16* __restrict__ outb, const float* __restrict__ bias,
    float qs, u16* __restrict__ vtp,
    u16* __restrict__ p0, u16* __restrict__ p1,
    u16* __restrict__ p2, u16* __restrict__ p3) {
  __shared__ __align__(16) u16 lA[128 * 64];   // 16 KB, 8 chunks/row, xor-swz
  __shared__ __align__(16) u16 lB[128 * 64];   // 16 KB
  const int tid = threadIdx.x;
  const int lane = tid & 63, w = tid >> 6;
  const int quad = lane >> 4, l15 = lane & 15;
  const int wm = w >> 1, wn = w & 1;
  const int bm = blockIdx.y, bn = blockIdx.x;
  const int Ksub = K / gridDim.z;
  const int k0 = blockIdx.z * Ksub;

  fx4 acc[4][4] = {};

  for (int kt = k0; kt < k0 + Ksub; kt += 64) {
    __syncthreads();
    #pragma unroll
    for (int t = 0; t < 4; t++) {
      int p = t * 256 + tid;
      int m = p >> 3, qp = p & 7, ql = qp ^ (m & 7);
      async16(A + (size_t)(bm * 128 + m) * K + kt + ql * 8,
              (char*)lA + t * 4096 + w * 1024);
    }
    #pragma unroll
    for (int t = 0; t < 4; t++) {
      int p = t * 256 + tid;
      int n = p >> 3, qp = p & 7, ql = qp ^ (n & 7);
      async16(Bt + (size_t)(bn * 128 + n) * K + kt + ql * 8,
              (char*)lB + t * 4096 + w * 1024);
    }
    __syncthreads();
    #pragma unroll
    for (int kk = 0; kk < 2; kk++) {
      s16x8 af[4], bfr[4];
      #pragma unroll
      for (int i = 0; i < 4; i++) {
        int m = wm * 64 + i * 16 + l15;
        af[i] = *(const s16x8*)((const char*)lA + m * 128 +
                                (((kk * 4 + quad) ^ (m & 7)) * 16));
      }
      #pragma unroll
      for (int j = 0; j < 4; j++) {
        int n = wn * 64 + j * 16 + l15;
        bfr[j] = *(const s16x8*)((const char*)lB + n * 128 +
                                 (((kk * 4 + quad) ^ (n & 7)) * 16));
      }
      #pragma unroll
      for (int i = 0; i < 4; i++)
        #pragma unroll
        for (int j = 0; j < 4; j++)
          acc[i][j] = __builtin_amdgcn_mfma_f32_16x16x32_bf16(af[i], bfr[j], acc[i][j], 0, 0, 0);
    }
  }

  u16* pb = nullptr;
  if (EPI == 3)
    pb = blockIdx.z == 0 ? p0 : blockIdx.z == 1 ? p1 : blockIdx.z == 2 ? p2 : p3;

  #pragma unroll
  for (int i = 0; i < 4; i++)
    #pragma unroll
    for (int j = 0; j < 4; j++) {
      int row0 = bm * 128 + wm * 64 + i * 16 + quad * 4;
      int col = bn * 128 + wn * 64 + j * 16 + l15;
      if (EPI == 0) {
        if (vtp != nullptr && col >= 1536) {
          // V region -> transposed store: Vt[(b*768 + col-1536)][tok]
          int bb = row0 >> 11, t0 = row0 & 2047;
          ushort4 pk = {f2bf(acc[i][j][0]), f2bf(acc[i][j][1]),
                        f2bf(acc[i][j][2]), f2bf(acc[i][j][3])};
          *(ushort4*)(vtp + ((size_t)(bb * 768 + (col - 1536)) << 11) + t0) = pk;
        } else {
          float sc = (col < 768) ? qs : 1.f;
          for (int r = 0; r < 4; r++)
            outb[(size_t)(row0 + r) * N + col] = f2bf(acc[i][j][r] * sc);
        }
      } else if (EPI == 2) {
        for (int r = 0; r < 4; r++)
          outb[(size_t)(row0 + r) * N + col] = f2bf(fmaxf(acc[i][j][r] + bias[col], 0.f));
      } else {
        for (int r = 0; r < 4; r++)
          pb[(size_t)(row0 + r) * N + col] = f2bf(acc[i][j][r]);
      }
    }
}

// ---------------- Flash attention v3 ---------------------------------------
// grid (qt=16, bh=24, sp=2), 512 threads (8 waves). Block: 128 q-rows x 1024
// keys (16 iters of 64). Wave w owns q-slice qt*128 + w*16 (q = l15).
__global__ __launch_bounds__(512) void attn_kernel(
    const u16* __restrict__ qkv, const u16* __restrict__ vt,
    const float* __restrict__ maskadd,
    u16* __restrict__ pO0, u16* __restrict__ pO1, float* __restrict__ pL) {
  __shared__ __align__(16) u16 sQ[128 * 64];     // 16 KB, xor-swizzled chunks
  __shared__ __align__(16) u16 sK[64 * 64];      //  8 KB, xor-swizzled chunks
  __shared__ __align__(16) u16 sV[64 * 68];      //  8.5 KB, 136B padded rows
  __shared__ __align__(16) float smask[1024];
  const int bh = blockIdx.y, b = bh / NH, h = bh % NH;
  const int qt = blockIdx.x, sp = blockIdx.z;
  const int tid = threadIdx.x, lane = tid & 63, w = tid >> 6;
  const int quad = lane >> 4, l15 = lane & 15;

  for (int i = 0; i < 2; i++) {
    int p = i * 512 + tid;
    int m = p >> 3, qp = p & 7, ql = qp ^ (m & 7);
    async16(qkv + (size_t)(b * TT + qt * 128 + m) * 2304 + h * HS + ql * 8,
            (char*)sQ + i * 8192 + w * 1024);
  }
  smask[tid]       = maskadd[b * TT + sp * 1024 + tid];
  smask[tid + 512] = maskadd[b * TT + sp * 1024 + 512 + tid];
  const u16* vbase = vt + (size_t)bh * HS * TT + (size_t)(tid >> 3) * TT + sp * 1024;
  s16x8 vcur = *(const s16x8*)(vbase + (tid & 7) * 8);
  __syncthreads();

  const int qrow = w * 16 + l15;
  s16x8 aq0 = *(const s16x8*)((const char*)sQ + qrow * 128 + ((quad ^ (l15 & 7)) * 16));
  s16x8 aq1 = *(const s16x8*)((const char*)sQ + qrow * 128 + (((4 + quad) ^ (l15 & 7)) * 16));

  const char* pK0 = (const char*)sK + l15 * 128 + ((quad ^ (l15 & 7)) * 16);
  const char* pK1 = (const char*)sK + l15 * 128 + (((4 + quad) ^ (l15 & 7)) * 16);
  const char* pV  = (const char*)sV + l15 * 136 + quad * 8;
  char* vwr = (char*)sV + (tid >> 3) * 136 + (tid & 7) * 16;

  float lsum = 0.f;
  fx4 o[4] = {};

  for (int kc = 0; kc < 16; kc++) {
    __syncthreads();
    {
      int m = tid >> 3, qp = tid & 7, ql = qp ^ (m & 7);
      async16(qkv + (size_t)(b * TT + sp * 1024 + kc * 64 + m) * 2304 + D_MODEL + h * HS + ql * 8,
              (char*)sK + w * 1024);
    }
    *(s16x8*)vwr = vcur;
    __syncthreads();
    int kn = (kc < 15) ? (kc + 1) * 64 : kc * 64;
    s16x8 vnxt = *(const s16x8*)(vbase + kn + (tid & 7) * 8);

    #pragma unroll
    for (int kt = 0; kt < 4; kt++) {
      float4 mb = *(const float4*)&smask[kc * 64 + kt * 16 + quad * 4];
      fx4 s = {mb.x, mb.y, mb.z, mb.w};
      s16x8 ak0 = *(const s16x8*)(pK0 + kt * 2048);
      s16x8 ak1 = *(const s16x8*)(pK1 + kt * 2048);
      s = __builtin_amdgcn_mfma_f32_16x16x32_bf16(ak0, aq0, s, 0, 0, 0);
      s = __builtin_amdgcn_mfma_f32_16x16x32_bf16(ak1, aq1, s, 0, 0, 0);
      float e0 = __builtin_amdgcn_exp2f(s[0]);
      float e1 = __builtin_amdgcn_exp2f(s[1]);
      float e2 = __builtin_amdgcn_exp2f(s[2]);
      float e3 = __builtin_amdgcn_exp2f(s[3]);
      lsum += (e0 + e1) + (e2 + e3);
      s16x4 pB = pack4(e0, e1, e2, e3);
      #pragma unroll
      for (int jv = 0; jv < 4; jv++) {
        s16x4 av = *(const s16x4*)(pV + jv * 2176 + kt * 32);
        o[jv] = __builtin_amdgcn_mfma_f32_16x16x16bf16_1k(av, pB, o[jv], 0, 0, 0);
      }
    }
    vcur = vnxt;
  }

  lsum += __shfl_xor(lsum, 16);
  lsum += __shfl_xor(lsum, 32);

  const int tile = bh * 32 + qt * 2 + (w >> 2);
  const int sub = (w & 3) * 16;
  u16* po = sp ? pO1 : pO0;
  size_t base = (size_t)tile * 4096;
  for (int jv = 0; jv < 4; jv++)
    for (int r = 0; r < 4; r++) {
      int vd = jv * 16 + quad * 4 + r;
      po[base + vd * 64 + sub + l15] = f2bf(o[jv][r]);
    }
  if (quad == 0) pL[sp * 49152 + tile * 64 + sub + l15] = lsum;
}

// ---- combine 2 key-splits: out[tok][hd] = (pO0+pO1)[vd][q] / (l0+l1)[q] ---
__global__ __launch_bounds__(256) void attn_reduce(
    const u16* __restrict__ pO0, const u16* __restrict__ pO1,
    const float* __restrict__ pL, u16* __restrict__ out) {
  __shared__ float T[64 * 65];
  __shared__ float rinv[64];
  const int tile = blockIdx.x;            // bh*32 + qt
  const int bh = tile >> 5, qt = tile & 31, b = bh / NH, h = bh % NH;
  const int t = threadIdx.x;
  if (t < 64) rinv[t] = 1.f / (pL[tile * 64 + t] + pL[49152 + tile * 64 + t]);
  __syncthreads();
  size_t base = (size_t)tile * 4096;
  for (int i = 0; i < 16; i++) {
    int idx = i * 256 + t, vd = idx >> 6, q = idx & 63;
    T[vd * 65 + q] = (bf2f(pO0[base + idx]) + bf2f(pO1[base + idx])) * rinv[q];
  }
  __syncthreads();
  int q = t >> 2, vb = (t & 3) * 16;
  u16* orow = out + (size_t)(b * TT + qt * 64 + q) * D_MODEL + h * HS + vb;
  for (int i = 0; i < 8; i++) {
    int vd = vb + i * 2;
    u32 pk = (u32)f2bf(T[vd * 65 + q]) | ((u32)f2bf(T[(vd + 1) * 65 + q]) << 16);
    *(u32*)(orow + i * 2) = pk;
  }
}

extern "C" void kernel_launch(void* const* d_in, const int* in_sizes, int n_in,
                              void* d_out, int out_size, void* d_ws, size_t ws_size,
                              hipStream_t stream) {
  const float* x    = (const float*)d_in[0];
  const int*   mask = (const int*)d_in[1];
  const float* Wq   = (const float*)d_in[2];
  const float* Wk   = (const float*)d_in[3];
  const float* Wv   = (const float*)d_in[4];
  const float* Wo   = (const float*)d_in[5];
  const float* bo   = (const float*)d_in[6];
  const float* g1   = (const float*)d_in[7];
  const float* be1  = (const float*)d_in[8];
  const float* g2   = (const float*)d_in[9];
  const float* be2  = (const float*)d_in[10];
  const float* W1   = (const float*)d_in[11];
  const float* bb1  = (const float*)d_in[12];
  const float* W2   = (const float*)d_in[13];
  const float* bb2  = (const float*)d_in[14];
  float* out = (float*)d_out;
  char* ws = (char*)d_ws;

  // workspace carve (bytes), total 64,503,808
  u16*   WqkvT = (u16*)(ws + 0);           //  3,538,944  [2304][768]
  u16*   WoT   = (u16*)(ws + 3538944);     //  1,179,648  [768][768]
  u16*   W1T   = (u16*)(ws + 4718592);     //  4,718,592  [3072][768]
  u16*   W2T   = (u16*)(ws + 9437184);     //  4,718,592  [768][3072]
  u16*   h1    = (u16*)(ws + 14155776);    //  6,291,456  [4096][768]; h2/pO0 alias
  u16*   QKV   = (u16*)(ws + 20447232);    // 18,874,368  [4096][2304]
  u16*   Vt    = (u16*)(ws + 39321600);    //  6,291,456  [24][64][2048]
  u16*   attn  = (u16*)(ws + 45613056);    //  6,291,456  [4096][768]
  float* yv    = (float*)(ws + 51904512);  // 12,582,912  [4096][768]
  float* mbias = yv;                       // 16,384 B; dead before Wo writes yv
  u16*   pO0   = h1;                       // attn partial split 0 (h1 dead)
  u16*   pO1   = (u16*)(ws + 51920896);    // 6,291,456 inside yv after mbias
  float* pL    = (float*)(ws + 58212352);  // 393,216  [2][768][64]
  u16*   h2    = h1;
  u16*   ff1   = QKV;                      // 25,165,824 spans QKV+Vt
  // Wo partials (4 x 6,291,456): QKV+Vt span (dead after attn)
  u16* pw0 = (u16*)(ws + 20447232);
  u16* pw1 = (u16*)(ws + 26738688);
  u16* pw2 = (u16*)(ws + 33030144);
  u16* pw3 = (u16*)(ws + 39321600);
  // FF2 partials (3 x 6,291,456)
  u16* pf0 = (u16*)(ws + 0);               // weight-head region (dead)
  u16* pf1 = (u16*)(ws + 14155776);        // h2 (dead after FF1)
  u16* pf2 = (u16*)(ws + 45613056);        // attn (dead after Wo)

  const float QS = 0.05205875399f;  // 768^-0.5 * log2(e)

  preproc<<<11024, 256, 0, stream>>>(x, mask, Wq, Wk, Wv, Wo, W1, W2,
                                     g1, be1, WqkvT, WoT, W1T, W2T, h1, mbias);
  // QKV: writes Q (scaled), K into QKV buffer; V directly transposed to Vt
  gemm_bt<0><<<dim3(18, 32, 1), 256, 0, stream>>>(h1, WqkvT, 4096, 2304, 768,
      QKV, nullptr, QS, Vt, nullptr, nullptr, nullptr, nullptr);
  attn_kernel<<<dim3(16, 24, 2), 512, 0, stream>>>(QKV, Vt, mbias, pO0, pO1, pL);
  attn_reduce<<<768, 256, 0, stream>>>(pO0, pO1, pL, attn);
  // Wo: split-K=4 -> 768 blocks (3/CU)
  gemm_bt<3><<<dim3(6, 32, 4), 256, 0, stream>>>(attn, WoT, 4096, 768, 768,
      nullptr, nullptr, 1.f, nullptr, pw0, pw1, pw2, pw3);
  red_wo_ln<<<4096, 256, 0, stream>>>(pw0, pw1, pw2, pw3, x, bo, g2, be2, yv, h2);
  gemm_bt<2><<<dim3(24, 32, 1), 256, 0, stream>>>(h2, W1T, 4096, 3072, 768,
      ff1, bb1, 1.f, nullptr, nullptr, nullptr, nullptr, nullptr);
  // FF2: split-K=3 -> 576 blocks (2.25/CU)
  gemm_bt<3><<<dim3(6, 32, 3), 256, 0, stream>>>(ff1, W2T, 4096, 768, 3072,
      nullptr, nullptr, 1.f, nullptr, pf0, pf1, pf2, nullptr);
  red_ff2<<<3072, 256, 0, stream>>>(pf0, pf1, pf2, yv, bb2, out);
}

// Round 7
// 270.797 us; speedup vs baseline: 1.1955x; 1.0245x over previous
//
#include <hip/hip_runtime.h>
#include <hip/hip_bf16.h>

// Transformer block: x[2,2048,768] fp32. GEMMs bf16 MFMA 16x16x32, 64x128
// tiles (4 waves of 32x64), BK=64, fp32 accumulate. N=768 GEMMs (Wo, FF2)
// split-K=2 with bf16 partials. QKV epilogue writes V directly transposed.
// Attention: S^T = K.Q^T (16x16x32); P^T C-frag feeds O^T = V^T.P^T B-frag
// (16x16x16 identity); KV-chunk 128; fixed-shift softmax, split over keys.

typedef unsigned short u16;
typedef unsigned int u32;
typedef __attribute__((ext_vector_type(8))) short s16x8;   // 8 bf16 (4 VGPR)
typedef __attribute__((ext_vector_type(4))) short s16x4;   // 4 bf16 (2 VGPR)
typedef __attribute__((ext_vector_type(4))) float fx4;     // 4 fp32 acc

#define D_MODEL 768
#define NH 12
#define HS 64
#define TT 2048
#define BB 2

__device__ __forceinline__ u16 f2bf(float f) {
  union { float f; u32 u; } v; v.f = f;
  u32 r = v.u + 0x7fffu + ((v.u >> 16) & 1u);   // RNE
  return (u16)(r >> 16);
}
__device__ __forceinline__ float bf2f(u16 h) {
  union { u32 u; float f; } v; v.u = ((u32)h) << 16; return v.f;
}
__device__ __forceinline__ s16x4 pack4(float a, float b, float c, float d) {
  union { __hip_bfloat162 h2[2]; s16x4 v; } u;
  u.h2[0] = __float22bfloat162_rn({a, b});
  u.h2[1] = __float22bfloat162_rn({c, d});
  return u.v;
}

// async global->LDS, 16B per lane; LDS dest = wave-uniform base + lane*16
__device__ __forceinline__ void async16(const void* g, void* l) {
  __builtin_amdgcn_global_load_lds(
      (const __attribute__((address_space(1))) u32*)g,
      (__attribute__((address_space(3))) u32*)l, 16, 0, 0);
}

// ---------------- mega preprocessing kernel --------------------------------
// blocks [0,6912): weight transpose+convert tiles (Wq,Wk,Wv,Wo,W1,W2)
// blocks [6912,11008): LayerNorm1 rows      blocks [11008,11024): mask bias
__global__ __launch_bounds__(256) void preproc(
    const float* __restrict__ x, const int* __restrict__ mask,
    const float* __restrict__ Wq, const float* __restrict__ Wk,
    const float* __restrict__ Wv, const float* __restrict__ Wo,
    const float* __restrict__ W1, const float* __restrict__ W2,
    const float* __restrict__ g1, const float* __restrict__ be1,
    u16* __restrict__ WqkvT, u16* __restrict__ WoT,
    u16* __restrict__ W1T, u16* __restrict__ W2T,
    u16* __restrict__ h1, float* __restrict__ mb) {
  __shared__ float t[32][33];
  __shared__ float ss[4], ssq[4];
  const int bid = blockIdx.x, tid = threadIdx.x;
  if (bid < 6912) {
    const float* in; u16* out; int R, C, cx, cy;
    if (bid < 1728) {
      int wsel = bid / 576, s = bid % 576;
      in = wsel == 0 ? Wq : wsel == 1 ? Wk : Wv;
      out = WqkvT + (size_t)wsel * 768 * 768;
      R = 768; C = 768; cx = s % 24; cy = s / 24;
    } else if (bid < 2304) {
      int s = bid - 1728; in = Wo; out = WoT;
      R = 768; C = 768; cx = s % 24; cy = s / 24;
    } else if (bid < 4608) {
      int s = bid - 2304; in = W1; out = W1T;
      R = 768; C = 3072; cx = s % 96; cy = s / 96;
    } else {
      int s = bid - 4608; in = W2; out = W2T;
      R = 3072; C = 768; cx = s % 24; cy = s / 24;
    }
    int c0 = cx * 32, r0 = cy * 32, xx = tid & 31, yy = tid >> 5;
    for (int i = 0; i < 4; i++)
      t[yy + i * 8][xx] = in[(size_t)(r0 + yy + i * 8) * C + c0 + xx];
    __syncthreads();
    for (int i = 0; i < 4; i++)
      out[(size_t)(c0 + yy + i * 8) * R + r0 + xx] = f2bf(t[xx][yy + i * 8]);
  } else if (bid < 11008) {
    int row = bid - 6912;
    const float* xr = x + (size_t)row * D_MODEL;
    float v0 = xr[tid], v1 = xr[tid + 256], v2 = xr[tid + 512];
    float s = v0 + v1 + v2, sq = v0 * v0 + v1 * v1 + v2 * v2;
    for (int m = 1; m < 64; m <<= 1) { s += __shfl_xor(s, m); sq += __shfl_xor(sq, m); }
    int w = tid >> 6;
    if ((tid & 63) == 0) { ss[w] = s; ssq[w] = sq; }
    __syncthreads();
    s = ss[0] + ss[1] + ss[2] + ss[3];
    sq = ssq[0] + ssq[1] + ssq[2] + ssq[3];
    float mean = s * (1.f / D_MODEL);
    float var = sq * (1.f / D_MODEL) - mean * mean;
    float rstd = rsqrtf(var + 1e-5f);
    u16* orow = h1 + (size_t)row * D_MODEL;
    orow[tid]       = f2bf((v0 - mean) * rstd * g1[tid]       + be1[tid]);
    orow[tid + 256] = f2bf((v1 - mean) * rstd * g1[tid + 256] + be1[tid + 256]);
    orow[tid + 512] = f2bf((v2 - mean) * rstd * g1[tid + 512] + be1[tid + 512]);
  } else {
    int i = (bid - 11008) * 256 + tid;
    mb[i] = mask[i] ? 0.f : -1e30f;
  }
}

// ---- partial-sum(2, bf16) + residual + bias + LayerNorm -> yv fp32, h2 bf16
__global__ __launch_bounds__(256) void red_wo_ln(
    const u16* __restrict__ p0, const u16* __restrict__ p1,
    const float* __restrict__ x, const float* __restrict__ bo,
    const float* __restrict__ g, const float* __restrict__ be,
    float* __restrict__ yv, u16* __restrict__ h2) {
  int row = blockIdx.x, tid = threadIdx.x;
  size_t base = (size_t)row * D_MODEL;
  float v[3];
  float s = 0.f, sq = 0.f;
  for (int i = 0; i < 3; i++) {
    int c = tid + i * 256;
    size_t idx = base + c;
    float t = bf2f(p0[idx]) + bf2f(p1[idx]) + x[idx] + bo[c];
    v[i] = t; yv[idx] = t;
    s += t; sq += t * t;
  }
  for (int m = 1; m < 64; m <<= 1) { s += __shfl_xor(s, m); sq += __shfl_xor(sq, m); }
  __shared__ float ss[4], ssq[4];
  int w = tid >> 6;
  if ((tid & 63) == 0) { ss[w] = s; ssq[w] = sq; }
  __syncthreads();
  s = ss[0] + ss[1] + ss[2] + ss[3];
  sq = ssq[0] + ssq[1] + ssq[2] + ssq[3];
  float mean = s * (1.f / D_MODEL);
  float var = sq * (1.f / D_MODEL) - mean * mean;
  float rstd = rsqrtf(var + 1e-5f);
  for (int i = 0; i < 3; i++) {
    int c = tid + i * 256;
    h2[base + c] = f2bf((v[i] - mean) * rstd * g[c] + be[c]);
  }
}

// ---- partial-sum(2, bf16) + residual + bias -> out fp32 (vectorized x4) ---
__global__ __launch_bounds__(256) void red_ff2(
    const u16* __restrict__ p0, const u16* __restrict__ p1,
    const float* __restrict__ yv,
    const float* __restrict__ bias, float* __restrict__ out) {
  size_t i = ((size_t)blockIdx.x * 256 + threadIdx.x) * 4;
  int col = (int)(i % D_MODEL);
  ushort4 a = *(const ushort4*)(p0 + i);
  ushort4 b = *(const ushort4*)(p1 + i);
  float4 y = *(const float4*)(yv + i);
  float4 o;
  o.x = bf2f(a.x) + bf2f(b.x) + y.x + bias[col];
  o.y = bf2f(a.y) + bf2f(b.y) + y.y + bias[col + 1];
  o.z = bf2f(a.z) + bf2f(b.z) + y.z + bias[col + 2];
  o.w = bf2f(a.w) + bf2f(b.w) + y.w + bias[col + 3];
  *(float4*)(out + i) = o;
}

// ---------------- GEMM: C[M][N] = A[M][K](bf16) * Bt[N][K](bf16)^T ---------
// 64x128 tile, BK=64, 4 waves 2x2 (wave tile 32x64, acc 2x4). Grid doubles
// vs 128-tile -> 4.5-6 blocks/CU for stall hiding. Split-K=2 via gridDim.z.
// EPI 0: bf16 out, cols<768 scaled by qs; if vtp set, cols>=1536 (V region)
// transposed to vtp. EPI 2: relu(acc+bias). EPI 3: bf16 partial -> p[z].
template <int EPI>
__global__ __launch_bounds__(256) void gemm_bt(
    const u16* __restrict__ A, const u16* __restrict__ Bt,
    int M, int N, int K,
    u16* __restrict__ outb, const float* __restrict__ bias,
    float qs, u16* __restrict__ vtp,
    u16* __restrict__ p0, u16* __restrict__ p1) {
  __shared__ __align__(16) u16 lA[64 * 64];    //  8 KB, 8 chunks/row, xor-swz
  __shared__ __align__(16) u16 lB[128 * 64];   // 16 KB
  const int tid = threadIdx.x;
  const int lane = tid & 63, w = tid >> 6;
  const int quad = lane >> 4, l15 = lane & 15;
  const int wm = w >> 1, wn = w & 1;
  const int bm = blockIdx.y, bn = blockIdx.x;
  const int Ksub = K / gridDim.z;
  const int k0 = blockIdx.z * Ksub;

  fx4 acc[2][4] = {};

  for (int kt = k0; kt < k0 + Ksub; kt += 64) {
    __syncthreads();
    #pragma unroll
    for (int t = 0; t < 2; t++) {
      int p = t * 256 + tid;
      int m = p >> 3, qp = p & 7, ql = qp ^ (m & 7);
      async16(A + (size_t)(bm * 64 + m) * K + kt + ql * 8,
              (char*)lA + t * 4096 + w * 1024);
    }
    #pragma unroll
    for (int t = 0; t < 4; t++) {
      int p = t * 256 + tid;
      int n = p >> 3, qp = p & 7, ql = qp ^ (n & 7);
      async16(Bt + (size_t)(bn * 128 + n) * K + kt + ql * 8,
              (char*)lB + t * 4096 + w * 1024);
    }
    __syncthreads();
    #pragma unroll
    for (int kk = 0; kk < 2; kk++) {
      s16x8 af[2], bfr[4];
      #pragma unroll
      for (int i = 0; i < 2; i++) {
        int m = wm * 32 + i * 16 + l15;
        af[i] = *(const s16x8*)((const char*)lA + m * 128 +
                                (((kk * 4 + quad) ^ (m & 7)) * 16));
      }
      #pragma unroll
      for (int j = 0; j < 4; j++) {
        int n = wn * 64 + j * 16 + l15;
        bfr[j] = *(const s16x8*)((const char*)lB + n * 128 +
                                 (((kk * 4 + quad) ^ (n & 7)) * 16));
      }
      #pragma unroll
      for (int i = 0; i < 2; i++)
        #pragma unroll
        for (int j = 0; j < 4; j++)
          acc[i][j] = __builtin_amdgcn_mfma_f32_16x16x32_bf16(af[i], bfr[j], acc[i][j], 0, 0, 0);
    }
  }

  u16* pb = (EPI == 3) ? (blockIdx.z == 0 ? p0 : p1) : nullptr;

  #pragma unroll
  for (int i = 0; i < 2; i++)
    #pragma unroll
    for (int j = 0; j < 4; j++) {
      int row0 = bm * 64 + wm * 32 + i * 16 + quad * 4;
      int col = bn * 128 + wn * 64 + j * 16 + l15;
      if (EPI == 0) {
        if (vtp != nullptr && col >= 1536) {
          // V region -> transposed store: Vt[(b*768 + col-1536)][tok]
          int bb = row0 >> 11, t0 = row0 & 2047;
          ushort4 pk = {f2bf(acc[i][j][0]), f2bf(acc[i][j][1]),
                        f2bf(acc[i][j][2]), f2bf(acc[i][j][3])};
          *(ushort4*)(vtp + ((size_t)(bb * 768 + (col - 1536)) << 11) + t0) = pk;
        } else {
          float sc = (col < 768) ? qs : 1.f;
          for (int r = 0; r < 4; r++)
            outb[(size_t)(row0 + r) * N + col] = f2bf(acc[i][j][r] * sc);
        }
      } else if (EPI == 2) {
        for (int r = 0; r < 4; r++)
          outb[(size_t)(row0 + r) * N + col] = f2bf(fmaxf(acc[i][j][r] + bias[col], 0.f));
      } else {
        for (int r = 0; r < 4; r++)
          pb[(size_t)(row0 + r) * N + col] = f2bf(acc[i][j][r]);
      }
    }
}

// ---------------- Flash attention v4: KV-chunk 128 -------------------------
// grid (qt=16, bh=24, sp=2), 512 threads (8 waves). Block: 128 q-rows x 1024
// keys (8 iters of 128 -> half the barrier drains of v3).
__global__ __launch_bounds__(512) void attn_kernel(
    const u16* __restrict__ qkv, const u16* __restrict__ vt,
    const float* __restrict__ maskadd,
    u16* __restrict__ pO0, u16* __restrict__ pO1, float* __restrict__ pL) {
  __shared__ __align__(16) u16 sQ[128 * 64];     // 16 KB, xor-swizzled chunks
  __shared__ __align__(16) u16 sK[128 * 64];     // 16 KB, xor-swizzled chunks
  __shared__ __align__(16) u16 sV[64 * 132];     // 16.9 KB, 264B padded rows
  __shared__ __align__(16) float smask[1024];
  const int bh = blockIdx.y, b = bh / NH, h = bh % NH;
  const int qt = blockIdx.x, sp = blockIdx.z;
  const int tid = threadIdx.x, lane = tid & 63, w = tid >> 6;
  const int quad = lane >> 4, l15 = lane & 15;

  for (int i = 0; i < 2; i++) {
    int p = i * 512 + tid;
    int m = p >> 3, qp = p & 7, ql = qp ^ (m & 7);
    async16(qkv + (size_t)(b * TT + qt * 128 + m) * 2304 + h * HS + ql * 8,
            (char*)sQ + i * 8192 + w * 1024);
  }
  smask[tid]       = maskadd[b * TT + sp * 1024 + tid];
  smask[tid + 512] = maskadd[b * TT + sp * 1024 + 512 + tid];
  // V register prefetch: vd = tid>>3, 16 keys (32B) per thread per iter
  const u16* vbase = vt + (size_t)bh * HS * TT + (size_t)(tid >> 3) * TT + sp * 1024;
  s16x8 vc0 = *(const s16x8*)(vbase + (tid & 7) * 16);
  s16x8 vc1 = *(const s16x8*)(vbase + (tid & 7) * 16 + 8);
  __syncthreads();

  const int qrow = w * 16 + l15;
  s16x8 aq0 = *(const s16x8*)((const char*)sQ + qrow * 128 + ((quad ^ (l15 & 7)) * 16));
  s16x8 aq1 = *(const s16x8*)((const char*)sQ + qrow * 128 + (((4 + quad) ^ (l15 & 7)) * 16));

  const char* pK0 = (const char*)sK + l15 * 128 + ((quad ^ (l15 & 7)) * 16);
  const char* pK1 = (const char*)sK + l15 * 128 + (((4 + quad) ^ (l15 & 7)) * 16);
  const char* pV  = (const char*)sV + l15 * 264 + quad * 8;
  char* vwr = (char*)sV + (tid >> 3) * 264 + (tid & 7) * 32;

  float lsum = 0.f;
  fx4 o[4] = {};

  for (int kc = 0; kc < 8; kc++) {
    __syncthreads();
    #pragma unroll
    for (int i = 0; i < 2; i++) {   // stage K chunk (128 keys x 64 hs)
      int p = i * 512 + tid;
      int m = p >> 3, qp = p & 7, ql = qp ^ (m & 7);
      async16(qkv + (size_t)(b * TT + sp * 1024 + kc * 128 + m) * 2304 + D_MODEL + h * HS + ql * 8,
              (char*)sK + i * 8192 + w * 1024);
    }
    *(s16x8*)vwr = vc0;             // V tile (padded rows) from registers
    *(s16x8*)(vwr + 16) = vc1;
    __syncthreads();
    int kn = (kc < 7 ? kc + 1 : kc) * 128;
    s16x8 vn0 = *(const s16x8*)(vbase + kn + (tid & 7) * 16);
    s16x8 vn1 = *(const s16x8*)(vbase + kn + (tid & 7) * 16 + 8);

    #pragma unroll
    for (int kt = 0; kt < 8; kt++) {
      float4 mb = *(const float4*)&smask[kc * 128 + kt * 16 + quad * 4];
      fx4 s = {mb.x, mb.y, mb.z, mb.w};
      s16x8 ak0 = *(const s16x8*)(pK0 + kt * 2048);
      s16x8 ak1 = *(const s16x8*)(pK1 + kt * 2048);
      s = __builtin_amdgcn_mfma_f32_16x16x32_bf16(ak0, aq0, s, 0, 0, 0);
      s = __builtin_amdgcn_mfma_f32_16x16x32_bf16(ak1, aq1, s, 0, 0, 0);
      float e0 = __builtin_amdgcn_exp2f(s[0]);
      float e1 = __builtin_amdgcn_exp2f(s[1]);
      float e2 = __builtin_amdgcn_exp2f(s[2]);
      float e3 = __builtin_amdgcn_exp2f(s[3]);
      lsum += (e0 + e1) + (e2 + e3);
      s16x4 pB = pack4(e0, e1, e2, e3);
      #pragma unroll
      for (int jv = 0; jv < 4; jv++) {
        s16x4 av = *(const s16x4*)(pV + jv * 4224 + kt * 32);
        o[jv] = __builtin_amdgcn_mfma_f32_16x16x16bf16_1k(av, pB, o[jv], 0, 0, 0);
      }
    }
    vc0 = vn0; vc1 = vn1;
  }

  lsum += __shfl_xor(lsum, 16);
  lsum += __shfl_xor(lsum, 32);

  const int tile = bh * 32 + qt * 2 + (w >> 2);
  const int sub = (w & 3) * 16;
  u16* po = sp ? pO1 : pO0;
  size_t base = (size_t)tile * 4096;
  for (int jv = 0; jv < 4; jv++)
    for (int r = 0; r < 4; r++) {
      int vd = jv * 16 + quad * 4 + r;
      po[base + vd * 64 + sub + l15] = f2bf(o[jv][r]);
    }
  if (quad == 0) pL[sp * 49152 + tile * 64 + sub + l15] = lsum;
}

// ---- combine 2 key-splits: out[tok][hd] = (pO0+pO1)[vd][q] / (l0+l1)[q] ---
__global__ __launch_bounds__(256) void attn_reduce(
    const u16* __restrict__ pO0, const u16* __restrict__ pO1,
    const float* __restrict__ pL, u16* __restrict__ out) {
  __shared__ float T[64 * 65];
  __shared__ float rinv[64];
  const int tile = blockIdx.x;            // bh*32 + qt
  const int bh = tile >> 5, qt = tile & 31, b = bh / NH, h = bh % NH;
  const int t = threadIdx.x;
  if (t < 64) rinv[t] = 1.f / (pL[tile * 64 + t] + pL[49152 + tile * 64 + t]);
  __syncthreads();
  size_t base = (size_t)tile * 4096;
  for (int i = 0; i < 16; i++) {
    int idx = i * 256 + t, vd = idx >> 6, q = idx & 63;
    T[vd * 65 + q] = (bf2f(pO0[base + idx]) + bf2f(pO1[base + idx])) * rinv[q];
  }
  __syncthreads();
  int q = t >> 2, vb = (t & 3) * 16;
  u16* orow = out + (size_t)(b * TT + qt * 64 + q) * D_MODEL + h * HS + vb;
  for (int i = 0; i < 8; i++) {
    int vd = vb + i * 2;
    u32 pk = (u32)f2bf(T[vd * 65 + q]) | ((u32)f2bf(T[(vd + 1) * 65 + q]) << 16);
    *(u32*)(orow + i * 2) = pk;
  }
}

extern "C" void kernel_launch(void* const* d_in, const int* in_sizes, int n_in,
                              void* d_out, int out_size, void* d_ws, size_t ws_size,
                              hipStream_t stream) {
  const float* x    = (const float*)d_in[0];
  const int*   mask = (const int*)d_in[1];
  const float* Wq   = (const float*)d_in[2];
  const float* Wk   = (const float*)d_in[3];
  const float* Wv   = (const float*)d_in[4];
  const float* Wo   = (const float*)d_in[5];
  const float* bo   = (const float*)d_in[6];
  const float* g1   = (const float*)d_in[7];
  const float* be1  = (const float*)d_in[8];
  const float* g2   = (const float*)d_in[9];
  const float* be2  = (const float*)d_in[10];
  const float* W1   = (const float*)d_in[11];
  const float* bb1  = (const float*)d_in[12];
  const float* W2   = (const float*)d_in[13];
  const float* bb2  = (const float*)d_in[14];
  float* out = (float*)d_out;
  char* ws = (char*)d_ws;

  // workspace carve (bytes), total 64,503,808
  u16*   WqkvT = (u16*)(ws + 0);           //  3,538,944  [2304][768]
  u16*   WoT   = (u16*)(ws + 3538944);     //  1,179,648  [768][768]
  u16*   W1T   = (u16*)(ws + 4718592);     //  4,718,592  [3072][768]
  u16*   W2T   = (u16*)(ws + 9437184);     //  4,718,592  [768][3072]
  u16*   h1    = (u16*)(ws + 14155776);    //  6,291,456  [4096][768]; h2/pO0 alias
  u16*   QKV   = (u16*)(ws + 20447232);    // 18,874,368  [4096][2304]
  u16*   Vt    = (u16*)(ws + 39321600);    //  6,291,456  [24][64][2048]
  u16*   attn  = (u16*)(ws + 45613056);    //  6,291,456  [4096][768]
  float* yv    = (float*)(ws + 51904512);  // 12,582,912  [4096][768]
  float* mbias = yv;                       // 16,384 B; dead before Wo writes yv
  u16*   pO0   = h1;                       // attn partial split 0 (h1 dead)
  u16*   pO1   = (u16*)(ws + 51920896);    // 6,291,456 inside yv after mbias
  float* pL    = (float*)(ws + 58212352);  // 393,216  [2][768][64]
  u16*   h2    = h1;
  u16*   ff1   = QKV;                      // 25,165,824 spans QKV+Vt
  // Wo partials (2 x 6,291,456): QKV span (dead after attn)
  u16* pw0 = (u16*)(ws + 20447232);
  u16* pw1 = (u16*)(ws + 26738688);
  // FF2 partials (2 x 6,291,456)
  u16* pf0 = (u16*)(ws + 0);               // WqkvT+WoT+W1T-head (all dead)
  u16* pf1 = (u16*)(ws + 14155776);        // h2 (dead after FF1)

  const float QS = 0.05205875399f;  // 768^-0.5 * log2(e)

  preproc<<<11024, 256, 0, stream>>>(x, mask, Wq, Wk, Wv, Wo, W1, W2,
                                     g1, be1, WqkvT, WoT, W1T, W2T, h1, mbias);
  // QKV: Q (scaled), K into QKV buffer; V directly transposed to Vt
  gemm_bt<0><<<dim3(18, 64, 1), 256, 0, stream>>>(h1, WqkvT, 4096, 2304, 768,
      QKV, nullptr, QS, Vt, nullptr, nullptr);
  attn_kernel<<<dim3(16, 24, 2), 512, 0, stream>>>(QKV, Vt, mbias, pO0, pO1, pL);
  attn_reduce<<<768, 256, 0, stream>>>(pO0, pO1, pL, attn);
  // Wo: split-K=2 -> 768 blocks, Ksub=384
  gemm_bt<3><<<dim3(6, 64, 2), 256, 0, stream>>>(attn, WoT, 4096, 768, 768,
      nullptr, nullptr, 1.f, nullptr, pw0, pw1);
  red_wo_ln<<<4096, 256, 0, stream>>>(pw0, pw1, x, bo, g2, be2, yv, h2);
  gemm_bt<2><<<dim3(24, 64, 1), 256, 0, stream>>>(h2, W1T, 4096, 3072, 768,
      ff1, bb1, 1.f, nullptr, nullptr, nullptr);
  // FF2: split-K=2 -> 768 blocks, Ksub=1536
  gemm_bt<3><<<dim3(6, 64, 2), 256, 0, stream>>>(ff1, W2T, 4096, 768, 3072,
      nullptr, nullptr, 1.f, nullptr, pf0, pf1);
  red_ff2<<<3072, 256, 0, stream>>>(pf0, pf1, yv, bb2, out);
}